// Round 10
// baseline (751.707 us; speedup 1.0000x reference)
//
#include <hip/hip_runtime.h>
#include <hip/hip_bf16.h>
#include <cstdint>
#include <cstddef>

#define B_ 2
#define S_ 2048
#define E_ 4096
#define H_ 32
#define KVH_ 8
#define D_ 128
#define M_ (B_*S_)      // 4096 rows (B*S)
#define HD_ (H_*D_)     // 4096
#define KVD_ (KVH_*D_)  // 1024
#define NQKV_ 6144      // HD_ + 2*KVD_

typedef unsigned short u16;
typedef __attribute__((ext_vector_type(8))) short bf16x8;
typedef __attribute__((ext_vector_type(4))) float f32x4;
typedef __attribute__((ext_vector_type(16))) float f32x16;

__device__ __forceinline__ float bf2f(u16 u) {
  union { float f; uint32_t i; } v; v.i = ((uint32_t)u) << 16; return v.f;
}
__device__ __forceinline__ u16 f2bf(float f) {
  union { float f; uint32_t i; } v; v.f = f;
  uint32_t r = v.i + 0x7FFF + ((v.i >> 16) & 1);   // RNE
  return (u16)(r >> 16);
}

// async global->LDS, 16B per lane; LDS dest = wave-uniform base + lane*16
__device__ __forceinline__ void gload_lds16(const void* g, void* l) {
  __builtin_amdgcn_global_load_lds(
      (const __attribute__((address_space(1))) void*)g,
      (__attribute__((address_space(3))) void*)l, 16, 0, 0);
}

// ---------------- elementwise f32 -> bf16 ----------------
__global__ __launch_bounds__(256) void k_f2bf(const float* __restrict__ in,
                                              u16* __restrict__ out, int n) {
  int i = (blockIdx.x * 256 + threadIdx.x) * 4;
  if (i + 3 < n) {
    float4 v = *(const float4*)(in + i);
    *(ushort4*)(out + i) = make_ushort4(f2bf(v.x), f2bf(v.y), f2bf(v.z), f2bf(v.w));
  }
}

// ---------------- transpose-convert f32 [R][C] -> bf16 [C][R] ----------------
__global__ __launch_bounds__(256) void k_transpose_f2bf(const float* __restrict__ in,
                                                        u16* __restrict__ out, int R, int C) {
  __shared__ float tile[32][33];
  int c0 = blockIdx.x * 32, r0 = blockIdx.y * 32;
  int lx = threadIdx.x, ly = threadIdx.y;
#pragma unroll
  for (int yy = 0; yy < 32; yy += 8)
    tile[ly + yy][lx] = in[(size_t)(r0 + ly + yy) * C + c0 + lx];
  __syncthreads();
#pragma unroll
  for (int yy = 0; yy < 32; yy += 8)
    out[(size_t)(c0 + ly + yy) * R + r0 + lx] = f2bf(tile[lx][ly + yy]);
}

// ---------- transpose v cols of qkvlin -> vt [B][KVH][D][S] (bf16) ----------
__global__ __launch_bounds__(256) void k_transpose_v(const u16* __restrict__ vlin,
                                                     u16* __restrict__ vt, int stride) {
  __shared__ u16 tile[32][33];
  int bk = blockIdx.z;             // b*KVH + kvh
  int b = bk >> 3, kvh = bk & 7;
  int s0 = blockIdx.x * 32, d0 = blockIdx.y * 32;
  int lx = threadIdx.x, ly = threadIdx.y;
#pragma unroll
  for (int yy = 0; yy < 32; yy += 8)
    tile[ly + yy][lx] = vlin[(size_t)(b * S_ + s0 + ly + yy) * stride + kvh * D_ + d0 + lx];
  __syncthreads();
#pragma unroll
  for (int yy = 0; yy < 32; yy += 8)
    vt[((size_t)bk * D_ + d0 + ly + yy) * S_ + s0 + lx] = tile[lx][ly + yy];
}

// ---------------- RoPE sin/cos table [S][64] ----------------
__global__ __launch_bounds__(256) void k_table(float2* __restrict__ tab) {
  int i = blockIdx.x * 256 + threadIdx.x;
  if (i < S_ * 64) {
    int s = i >> 6, d = i & 63;
    float inv = powf(10000.0f, -(float)d / 64.0f);
    float f = (float)s * inv;
    tab[i] = make_float2(sinf(f), cosf(f));
  }
}

// -------- RoPE + head reorder: strided cols of [B,S,*] -> [B,heads,S,D] --------
__global__ __launch_bounds__(256) void k_rope(const u16* __restrict__ in, u16* __restrict__ out,
                                              const float2* __restrict__ tab,
                                              const int* __restrict__ pos,
                                              int heads, int in_stride, int total) {
  int i = blockIdx.x * 256 + threadIdx.x;
  if (i >= total) return;
  int d = i & 63;
  int s = (i >> 6) & (S_ - 1);
  int bh = i >> 17;                 // 64*S_ = 2^17
  int h = bh % heads, b = bh / heads;
  size_t ibase = ((size_t)(b * S_ + s)) * in_stride + h * D_;
  float2 scv = tab[pos[b * S_ + s] * 64 + d];
  float x1 = bf2f(in[ibase + d]), x2 = bf2f(in[ibase + d + 64]);
  size_t obase = ((size_t)bh * S_ + s) * D_;
  out[obase + d]      = f2bf(x1 * scv.y - x2 * scv.x);
  out[obase + d + 64] = f2bf(x2 * scv.y + x1 * scv.x);
}

// ---------------- bf16 GEMM v4: 8-phase 256x256, counted vmcnt ----------------
// C[M,N] = A[M,K] * BT[N,K]^T. BK=64 split into 4 k-slices of 16; phase p
// consumes slice p (staged exactly 4 phase-slots earlier) => constant
// s_waitcnt vmcnt(8) keeps 4 slice-stages (8 loads) in flight across barriers:
// loads NEVER drain (T4). One barrier/phase, double-buffered 128KB LDS,
// 8 waves (2Mx4N), per-wave 128x64 out via r7-verified 32x32x16 MFMA path.
// LDS unit layout: slice region = 512 units of 16B; unit(row,c) stored at
// physical unit 2*row + (c ^ ((row>>2)&1))  [bank XOR, involution, both sides]
// => 2-way reads (free). Staging pre-swizzles the GLOBAL source col-half.
template<bool OUTF32>
__global__ __launch_bounds__(512, 2) void k_gemm8(const u16* __restrict__ A,
                                                  const u16* __restrict__ BT,
                                                  void* __restrict__ Cp,
                                                  int M, int N, int K) {
  __shared__ __align__(16) u16 As[2 * 4 * 4096];   // [buf][ks][512 units][8]
  __shared__ __align__(16) u16 Bs[2 * 4 * 4096];
  const int tid = threadIdx.x;
  const int w = tid >> 6, lane = tid & 63;
  const int l32 = lane & 31, hi = lane >> 5;
  const int nbn = N >> 8;
  const int tm = blockIdx.x / nbn, tn = blockIdx.x % nbn;
  const int m0 = tm << 8, n0 = tn << 8;
  const int wm = w >> 2, wn = w & 3;               // 2 x 4 wave grid

  f32x16 acc[4][2] = {};

  // staging geometry: wave w covers physical units [w*64, w*64+64) of a slice
  const int prow = ((w << 6) + lane) >> 1;         // tile-local row 0..255
  const int cix  = (lane & 1) ^ ((prow >> 2) & 1); // logical col-half (swizzled src)
  const int nt = K >> 6;

  auto STAGE = [&](int b, int t, int p) {
    const int kk = (t << 6) + (p << 4) + (cix << 3);
    u16* la = As + ((b << 2) + p) * 4096 + (w << 9);
    u16* lb = Bs + ((b << 2) + p) * 4096 + (w << 9);
    gload_lds16(A  + (size_t)(m0 + prow) * K + kk, la);
    gload_lds16(BT + (size_t)(n0 + prow) * K + kk, lb);
  };

  // prologue: all 4 slices of tile 0 -> buf 0 (8 loads)
#pragma unroll
  for (int p = 0; p < 4; ++p) STAGE(0, 0, p);

  int cur = 0;
  for (int t = 0; t < nt; ++t) {
    const int t1 = (t + 1 < nt) ? t + 1 : nt - 1;  // clamp: dummy restage at end
#pragma unroll
    for (int p = 0; p < 4; ++p) {
      STAGE(cur ^ 1, t1, p);                       // issue-early (T14 essence)
      asm volatile("s_waitcnt vmcnt(8)" ::: "memory");  // slice p of tile t landed
      __builtin_amdgcn_s_barrier();
      asm volatile("" ::: "memory");

      const u16* ab = As + ((cur << 2) + p) * 4096;
      const u16* bb = Bs + ((cur << 2) + p) * 4096;
      int br0 = (wn << 6) + l32;
      int br1 = (wn << 6) + 32 + l32;
      bf16x8 b0 = *(const bf16x8*)(bb + (((br0 << 1) + (hi ^ ((br0 >> 2) & 1))) << 3));
      bf16x8 b1 = *(const bf16x8*)(bb + (((br1 << 1) + (hi ^ ((br1 >> 2) & 1))) << 3));
      __builtin_amdgcn_s_setprio(1);
#pragma unroll
      for (int mi = 0; mi < 4; ++mi) {
        int ar = (wm << 7) + (mi << 5) + l32;
        bf16x8 a = *(const bf16x8*)(ab + (((ar << 1) + (hi ^ ((ar >> 2) & 1))) << 3));
        acc[mi][0] = __builtin_amdgcn_mfma_f32_32x32x16_bf16(a, b0, acc[mi][0], 0, 0, 0);
        acc[mi][1] = __builtin_amdgcn_mfma_f32_32x32x16_bf16(a, b1, acc[mi][1], 0, 0, 0);
      }
      __builtin_amdgcn_s_setprio(0);
      // my ds_reads complete before I pass the next barrier (overwrite window)
      asm volatile("s_waitcnt lgkmcnt(0)" ::: "memory");
    }
    cur ^= 1;
  }

  // epilogue: C/D mapping per m74/m101 (r7-verified)
#pragma unroll
  for (int mi = 0; mi < 4; ++mi)
#pragma unroll
    for (int ni = 0; ni < 2; ++ni) {
      int col = n0 + (wn << 6) + (ni << 5) + l32;
#pragma unroll
      for (int r = 0; r < 16; ++r) {
        int row = m0 + (wm << 7) + (mi << 5) + (r & 3) + ((r >> 2) << 3) + (hi << 2);
        if (OUTF32) ((float*)Cp)[(size_t)row * N + col] = acc[mi][ni][r];
        else        ((u16*)Cp)[(size_t)row * N + col]  = f2bf(acc[mi][ni][r]);
      }
    }
}

// ---------------- flash attention v8: 2 blocks/CU via Ps split ----------------
// (unchanged from round 9 — verified)
__global__ __launch_bounds__(512, 4) void k_attn(const u16* __restrict__ QKV,
                                                 const u16* __restrict__ Kr,
                                                 const u16* __restrict__ Vt,
                                                 const float2* __restrict__ tab,
                                                 const int* __restrict__ pos,
                                                 u16* __restrict__ ctx) {
  __shared__ __align__(16) u16 Ks[2][64 * 128];
  __shared__ __align__(16) u16 Vs[2][128 * 64];
  __shared__ __align__(16) u16 Ps[8][16 * 40];   // pitch 40 (80B): <=2-way banks
  const int bid = blockIdx.x;
  const int qt = 15 - (bid >> 6);          // longest-first
  const int bh = bid & 63;
  const int b = bh >> 5, h = bh & 31;
  const int kvh = h >> 2;
  const int tid = threadIdx.x;
  const int w = tid >> 6, lane = tid & 63;
  const int lrow = lane & 15, lk = lane >> 4;
  const int q0w = qt * 128 + w * 16;       // wave's first q row

  // ---- Q frags with RoPE fused (Q read once from qkvlin) ----
  const int s = q0w + lrow;
  const int p = pos[b * S_ + s];
  const u16* q0 = QKV + ((size_t)(b * S_ + s)) * NQKV_ + h * D_ + lk * 8;
  bf16x8 raw[4];
#pragma unroll
  for (int ks = 0; ks < 4; ++ks) raw[ks] = *(const bf16x8*)(q0 + ks * 32);
  bf16x8 qf[4];
#pragma unroll
  for (int ks = 0; ks < 2; ++ks)
#pragma unroll
    for (int e = 0; e < 8; ++e) {
      int d = ks * 32 + lk * 8 + e;
      float2 scv = tab[p * 64 + d];
      float x1 = bf2f((u16)raw[ks][e]), x2 = bf2f((u16)raw[ks + 2][e]);
      qf[ks][e]     = (short)f2bf(x1 * scv.y - x2 * scv.x);
      qf[ks + 2][e] = (short)f2bf(x2 * scv.y + x1 * scv.x);
    }

  float m[4] = {-1e30f, -1e30f, -1e30f, -1e30f};   // log2-domain running max
  float l[4] = {0.f, 0.f, 0.f, 0.f};
  f32x4 o[8] = {};

  const u16* kbase = Kr + (size_t)(b * KVH_ + kvh) * S_ * D_;
  const u16* vbase = Vt + (size_t)(b * KVH_ + kvh) * D_ * S_;
  const float cl = 0.12751743435f;  // (1/sqrt(128)) * log2(e)
  const int nt = 2 * qt + 2;

  auto STAGE = [&](int buf, int kb) {
    const int kv0 = kb << 6;
#pragma unroll
    for (int c = 0; c < 2; ++c) {          // K: 8 rows/wave, 4 rows/call
      int r = w * 8 + (lane >> 4) + c * 4;
      gload_lds16(kbase + (size_t)(kv0 + r) * D_ + (((lane & 15) ^ (r & 7)) << 3),
                  &Ks[buf][(w * 8 + c * 4) * 128]);
    }
#pragma unroll
    for (int c = 0; c < 2; ++c) {          // V^T: 16 rows/wave, 8 rows/call
      int r = w * 16 + (lane >> 3) + c * 8;
      gload_lds16(vbase + (size_t)r * S_ + kv0 + (((lane & 7) ^ (r & 7)) << 3),
                  &Vs[buf][(w * 16 + c * 8) * 64]);
    }
  };

  STAGE(0, 0);
  int cur = 0;
  for (int kb = 0; kb < nt; ++kb) {
    __syncthreads();                       // drains prev stage (vmcnt) + prev reads
    if (kb + 1 < nt) STAGE(cur ^ 1, kb + 1);
    const int kv0 = kb << 6;
    if (kv0 <= q0w + 15) {                 // wave-active tile
      const u16* Kb = &Ks[cur][0];
      const u16* Vb = &Vs[cur][0];

      // S = Q K^T (16 MFMAs)
      f32x4 sc[4] = {};
      __builtin_amdgcn_s_setprio(1);
#pragma unroll
      for (int n0 = 0; n0 < 4; ++n0) {
#pragma unroll
        for (int ks = 0; ks < 4; ++ks) {
          int krow = (n0 << 4) + lrow;
          bf16x8 kf = *(const bf16x8*)(Kb + krow * 128 + ((((ks << 2) + lk) ^ (krow & 7)) << 3));
          sc[n0] = __builtin_amdgcn_mfma_f32_16x16x32_bf16(qf[ks], kf, sc[n0], 0, 0, 0);
        }
      }
      __builtin_amdgcn_s_setprio(0);

      // scale (log2 domain) + causal mask (global indices) + online softmax
      const bool diag = (kv0 + 63 > q0w);
      float mnew[4] = {m[0], m[1], m[2], m[3]};
#pragma unroll
      for (int n0 = 0; n0 < 4; ++n0)
#pragma unroll
        for (int j = 0; j < 4; ++j) {
          float v = sc[n0][j] * cl;
          if (diag && (kv0 + (n0 << 4) + lrow > q0w + (lk << 2) + j)) v = -1e30f;
          sc[n0][j] = v;
          mnew[j] = fmaxf(mnew[j], v);
        }
#pragma unroll
      for (int j = 0; j < 4; ++j) {
        float v = mnew[j];
        v = fmaxf(v, __shfl_xor(v, 1));
        v = fmaxf(v, __shfl_xor(v, 2));
        v = fmaxf(v, __shfl_xor(v, 4));
        v = fmaxf(v, __shfl_xor(v, 8));
        mnew[j] = v;
      }
      float alpha[4], rs[4] = {0.f, 0.f, 0.f, 0.f};
#pragma unroll
      for (int j = 0; j < 4; ++j) { alpha[j] = exp2f(m[j] - mnew[j]); m[j] = mnew[j]; }
#pragma unroll
      for (int n0 = 0; n0 < 4; ++n0)
#pragma unroll
        for (int j = 0; j < 4; ++j) {
          float pv = exp2f(sc[n0][j] - m[j]);
          sc[n0][j] = pv;
          rs[j] += pv;
        }
#pragma unroll
      for (int j = 0; j < 4; ++j) {
        float v = rs[j];
        v += __shfl_xor(v, 1); v += __shfl_xor(v, 2);
        v += __shfl_xor(v, 4); v += __shfl_xor(v, 8);
        l[j] = l[j] * alpha[j] + v;
      }
#pragma unroll
      for (int db = 0; db < 8; ++db)
#pragma unroll
        for (int j = 0; j < 4; ++j)
          o[db][j] *= alpha[j];

      // ---- O += P V in two kv-32 halves (Ps pitch 40, reused) ----
      u16* pw = &Ps[w][0];
#pragma unroll
      for (int half = 0; half < 2; ++half) {
        // WAR fence: prior pass's reads (and writes) drained before overwrite
        asm volatile("s_waitcnt lgkmcnt(0)" ::: "memory");
#pragma unroll
        for (int n0 = 0; n0 < 2; ++n0)
#pragma unroll
          for (int j = 0; j < 4; ++j)
            pw[((lk << 2) + j) * 40 + (n0 << 4) + lrow] =
                f2bf(sc[(half << 1) + n0][j]);
        bf16x8 pf = *(const bf16x8*)(pw + lrow * 40 + (lk << 3));
        __builtin_amdgcn_s_setprio(1);
#pragma unroll
        for (int db = 0; db < 8; ++db) {
          int dr = (db << 4) + lrow;
          bf16x8 vf = *(const bf16x8*)(Vb + dr * 64 + ((((half << 2) + lk) ^ (dr & 7)) << 3));
          o[db] = __builtin_amdgcn_mfma_f32_16x16x32_bf16(pf, vf, o[db], 0, 0, 0);
        }
        __builtin_amdgcn_s_setprio(0);
      }
    }
    cur ^= 1;
  }

#pragma unroll
  for (int j = 0; j < 4; ++j) l[j] = 1.0f / l[j];
#pragma unroll
  for (int db = 0; db < 8; ++db)
#pragma unroll
    for (int j = 0; j < 4; ++j) {
      int q = q0w + (lk << 2) + j;
      ctx[((size_t)(b * S_ + q)) * HD_ + h * D_ + (db << 4) + lrow] = f2bf(o[db][j] * l[j]);
    }
}

extern "C" void kernel_launch(void* const* d_in, const int* in_sizes, int n_in,
                              void* d_out, int out_size, void* d_ws, size_t ws_size,
                              hipStream_t stream) {
  const float* hidden = (const float*)d_in[0];
  const float* Wq = (const float*)d_in[1];
  const float* Wk = (const float*)d_in[2];
  const float* Wv = (const float*)d_in[3];
  const float* Wo = (const float*)d_in[4];
  const int* pos_ids = (const int*)d_in[7];

  char* ws = (char*)d_ws;
  u16* hs      = (u16*)(ws);                    // [0,32M)   hidden bf16; later ctx
  u16* ctx     = hs;                            //           ctx [B,S,H*D]
  u16* wqkvt   = (u16*)(ws + 33554432ull);      // [32,80M)  stacked [6144][4096]; later WoT
  u16* wot     = wqkvt;
  u16* qkvlin  = (u16*)(ws + 83886080ull);      // [80,128M) qkv_lin [M][6144]
  u16* kr      = (u16*)(ws + 134217728ull);     // [128,136M) k rope'd [B,KVH,S,D]
  u16* vt      = (u16*)(ws + 142606336ull);     // [136,144M) v^T [B,KVH,D,S]
  float2* tab  = (float2*)(ws + 150994944ull);  // [144,145M) sin/cos table

  // 1. hidden -> bf16
  k_f2bf<<<dim3((M_*E_)/1024), dim3(256), 0, stream>>>(hidden, hs, M_*E_);
  // 2. stacked W^T: rows [0,4096)=Wq^T, [4096,5120)=Wk^T, [5120,6144)=Wv^T
  k_transpose_f2bf<<<dim3(HD_/32, E_/32), dim3(32, 8), 0, stream>>>(Wq, wqkvt, E_, HD_);
  k_transpose_f2bf<<<dim3(KVD_/32, E_/32), dim3(32, 8), 0, stream>>>(Wk, wqkvt + (size_t)HD_*E_, E_, KVD_);
  k_transpose_f2bf<<<dim3(KVD_/32, E_/32), dim3(32, 8), 0, stream>>>(Wv, wqkvt + (size_t)(HD_+KVD_)*E_, E_, KVD_);
  // 3. fused QKV projection: [M][6144], 256^2 8-phase
  k_gemm8<false><<<dim3((M_/256)*(NQKV_/256)), dim3(512), 0, stream>>>(hs, wqkvt, (void*)qkvlin, M_, NQKV_, E_);
  // 4. Wo^T (reuses wqkvt region; QKV GEMM done)
  k_transpose_f2bf<<<dim3(E_/32, HD_/32), dim3(32, 8), 0, stream>>>(Wo, wot, HD_, E_);
  // 5. sin/cos table
  k_table<<<dim3((S_*64)/256), dim3(256), 0, stream>>>(tab);
  // 6. RoPE K -> kr [B,KVH,S,D] (Q rope is fused into k_attn)
  k_rope<<<dim3((B_*KVH_*S_*64)/256), dim3(256), 0, stream>>>(qkvlin + HD_, kr, tab, pos_ids, KVH_, NQKV_, B_*KVH_*S_*64);
  // 7. V transpose -> [B,KVH,D,S]
  k_transpose_v<<<dim3(S_/32, D_/32, B_*KVH_), dim3(32, 8), 0, stream>>>(qkvlin + HD_ + KVD_, vt, NQKV_);
  // 8. flash attention v8 -> ctx (hs region; hidden no longer needed)
  k_attn<<<dim3(B_*H_*(S_/128)), dim3(512), 0, stream>>>(qkvlin, kr, vt, tab, pos_ids, ctx);
  // 9. out = ctx @ Wo (fp32 epilogue), 256^2 8-phase
  k_gemm8<true><<<dim3((M_/256)*(E_/256)), dim3(512), 0, stream>>>(ctx, wot, d_out, M_, E_, HD_);
}

// Round 11
// 671.222 us; speedup vs baseline: 1.1199x; 1.1199x over previous
//
#include <hip/hip_runtime.h>
#include <hip/hip_bf16.h>
#include <cstdint>
#include <cstddef>

#define B_ 2
#define S_ 2048
#define E_ 4096
#define H_ 32
#define KVH_ 8
#define D_ 128
#define M_ (B_*S_)      // 4096 rows (B*S)
#define HD_ (H_*D_)     // 4096
#define KVD_ (KVH_*D_)  // 1024
#define NQKV_ 6144      // HD_ + 2*KVD_

typedef unsigned short u16;
typedef __attribute__((ext_vector_type(8))) short bf16x8;
typedef __attribute__((ext_vector_type(4))) float f32x4;
typedef __attribute__((ext_vector_type(16))) float f32x16;

__device__ __forceinline__ float bf2f(u16 u) {
  union { float f; uint32_t i; } v; v.i = ((uint32_t)u) << 16; return v.f;
}
__device__ __forceinline__ u16 f2bf(float f) {
  union { float f; uint32_t i; } v; v.f = f;
  uint32_t r = v.i + 0x7FFF + ((v.i >> 16) & 1);   // RNE
  return (u16)(r >> 16);
}

// async global->LDS, 16B per lane; LDS dest = wave-uniform base + lane*16
__device__ __forceinline__ void gload_lds16(const void* g, void* l) {
  __builtin_amdgcn_global_load_lds(
      (const __attribute__((address_space(1))) void*)g,
      (__attribute__((address_space(3))) void*)l, 16, 0, 0);
}

// ---------------- elementwise f32 -> bf16 ----------------
__global__ __launch_bounds__(256) void k_f2bf(const float* __restrict__ in,
                                              u16* __restrict__ out, int n) {
  int i = (blockIdx.x * 256 + threadIdx.x) * 4;
  if (i + 3 < n) {
    float4 v = *(const float4*)(in + i);
    *(ushort4*)(out + i) = make_ushort4(f2bf(v.x), f2bf(v.y), f2bf(v.z), f2bf(v.w));
  }
}

// ------- transpose-convert f32 [R][C] -> bf16 [C][R], 64x64, ushort2 stores ----
__global__ __launch_bounds__(256) void k_transpose_f2bf(const float* __restrict__ in,
                                                        u16* __restrict__ out, int R, int C) {
  __shared__ float tile[64][65];
  const int c0 = blockIdx.x * 64, r0 = blockIdx.y * 64;
  const int tid = threadIdx.x;
  const int lx = tid & 63, ty = tid >> 6;        // loads: 64-lane rows
#pragma unroll
  for (int i = 0; i < 16; ++i)
    tile[ty + 4 * i][lx] = in[(size_t)(r0 + ty + 4 * i) * C + c0 + lx];
  __syncthreads();
  const int oy = tid & 31, xb = tid >> 5;        // stores: 32 lanes x ushort2 = 128B
#pragma unroll
  for (int i = 0; i < 8; ++i) {
    int X = xb + 8 * i;
    *(ushort2*)(out + (size_t)(c0 + X) * R + r0 + 2 * oy) =
        make_ushort2(f2bf(tile[2 * oy][X]), f2bf(tile[2 * oy + 1][X]));
  }
}

// -- transpose v cols of qkvlin -> vt [B][KVH][D][S] (bf16), 64x64 vectorized --
__global__ __launch_bounds__(256) void k_transpose_v(const u16* __restrict__ vlin,
                                                     u16* __restrict__ vt, int stride) {
  __shared__ u16 tile[64][65];
  const int bk = blockIdx.z;             // b*KVH + kvh
  const int b = bk >> 3, kvh = bk & 7;
  const int s0 = blockIdx.x * 64, d0 = blockIdx.y * 64;
  const int tid = threadIdx.x;
  const int lx = tid & 63, ty = tid >> 6;
#pragma unroll
  for (int i = 0; i < 16; ++i)
    tile[ty + 4 * i][lx] =
        vlin[(size_t)(b * S_ + s0 + ty + 4 * i) * stride + kvh * D_ + d0 + lx];
  __syncthreads();
  const int oy = tid & 31, xb = tid >> 5;
#pragma unroll
  for (int i = 0; i < 8; ++i) {
    int X = xb + 8 * i;
    *(ushort2*)(vt + ((size_t)bk * D_ + d0 + X) * S_ + s0 + 2 * oy) =
        make_ushort2(tile[2 * oy][X], tile[2 * oy + 1][X]);
  }
}

// ---------------- RoPE sin/cos table [S][64] ----------------
__global__ __launch_bounds__(256) void k_table(float2* __restrict__ tab) {
  int i = blockIdx.x * 256 + threadIdx.x;
  if (i < S_ * 64) {
    int s = i >> 6, d = i & 63;
    float inv = powf(10000.0f, -(float)d / 64.0f);
    float f = (float)s * inv;
    tab[i] = make_float2(sinf(f), cosf(f));
  }
}

// -------- RoPE + head reorder: strided cols of [B,S,*] -> [B,heads,S,D] --------
__global__ __launch_bounds__(256) void k_rope(const u16* __restrict__ in, u16* __restrict__ out,
                                              const float2* __restrict__ tab,
                                              const int* __restrict__ pos,
                                              int heads, int in_stride, int total) {
  int i = blockIdx.x * 256 + threadIdx.x;
  if (i >= total) return;
  int d = i & 63;
  int s = (i >> 6) & (S_ - 1);
  int bh = i >> 17;                 // 64*S_ = 2^17
  int h = bh % heads, b = bh / heads;
  size_t ibase = ((size_t)(b * S_ + s)) * in_stride + h * D_;
  float2 scv = tab[pos[b * S_ + s] * 64 + d];
  float x1 = bf2f(in[ibase + d]), x2 = bf2f(in[ibase + d + 64]);
  size_t obase = ((size_t)bh * S_ + s) * D_;
  out[obase + d]      = f2bf(x1 * scv.y - x2 * scv.x);
  out[obase + d + 64] = f2bf(x2 * scv.y + x1 * scv.x);
}

// ---------------- bf16 GEMM: C[M,N] = A[M,K] * BT[N,K]^T ----------------
// 128x128 tile, BK=64, 4 waves (2x2), 32x32x16 MFMA (r7-verified layout).
// No XCD swizzle (r9: it tripled FETCH_SIZE). 2-barrier m97 structure at its
// measured ~845 TF ceiling.
template<bool OUTF32>
__global__ __launch_bounds__(256) void k_gemm_bt(const u16* __restrict__ A,
                                                 const u16* __restrict__ BT,
                                                 void* __restrict__ Cp,
                                                 int M, int N, int K) {
  __shared__ __align__(16) u16 As[128 * 64];
  __shared__ __align__(16) u16 Bs[128 * 64];
  const int tid = threadIdx.x;
  const int wid = tid >> 6, lane = tid & 63;
  const int l32 = lane & 31, hi = lane >> 5;
  const int nbn = N >> 7;
  const int tm = blockIdx.x / nbn, tn = blockIdx.x % nbn;
  const int m0 = tm << 7, n0 = tn << 7;
  const int wr = wid >> 1, wc = wid & 1;

  f32x16 acc[2][2] = {};
  const int srow = (wid << 3) + (lane >> 3);  // row within 32-row staging chunk
  const int sblk = lane & 7;

  for (int kt = 0; kt < K; kt += 64) {
#pragma unroll
    for (int c = 0; c < 4; ++c) {
      int r = (c << 5) + srow;
      int gb = sblk ^ (r & 7);   // pre-swizzle source so LDS reads are conflict-lite
      gload_lds16(A  + (size_t)(m0 + r) * K + kt + (gb << 3), As + (c << 11) + (wid << 9));
      gload_lds16(BT + (size_t)(n0 + r) * K + kt + (gb << 3), Bs + (c << 11) + (wid << 9));
    }
    __syncthreads();
    bf16x8 af[2][4], bfr[2][4];
#pragma unroll
    for (int mi = 0; mi < 2; ++mi)
#pragma unroll
      for (int ks = 0; ks < 4; ++ks) {
        int ar = (wr << 6) + (mi << 5) + l32;
        int cb = (ks << 1) + hi;
        af[mi][ks] = *(const bf16x8*)(As + ar * 64 + ((cb ^ (ar & 7)) << 3));
      }
#pragma unroll
    for (int ni = 0; ni < 2; ++ni)
#pragma unroll
      for (int ks = 0; ks < 4; ++ks) {
        int br = (wc << 6) + (ni << 5) + l32;
        int cb = (ks << 1) + hi;
        bfr[ni][ks] = *(const bf16x8*)(Bs + br * 64 + ((cb ^ (br & 7)) << 3));
      }
#pragma unroll
    for (int ks = 0; ks < 4; ++ks)
#pragma unroll
      for (int mi = 0; mi < 2; ++mi)
#pragma unroll
        for (int ni = 0; ni < 2; ++ni)
          acc[mi][ni] = __builtin_amdgcn_mfma_f32_32x32x16_bf16(af[mi][ks], bfr[ni][ks],
                                                                acc[mi][ni], 0, 0, 0);
    __syncthreads();
  }

#pragma unroll
  for (int mi = 0; mi < 2; ++mi)
#pragma unroll
    for (int ni = 0; ni < 2; ++ni) {
      int col = n0 + (wc << 6) + (ni << 5) + l32;
#pragma unroll
      for (int r = 0; r < 16; ++r) {
        int row = m0 + (wr << 6) + (mi << 5) + (r & 3) + ((r >> 2) << 3) + (hi << 2);
        if (OUTF32) ((float*)Cp)[(size_t)row * N + col] = acc[mi][ni][r];
        else        ((u16*)Cp)[(size_t)row * N + col]  = f2bf(acc[mi][ni][r]);
      }
    }
}

// ---------------- flash attention v9: v8 + T13 defer-max ----------------
// v8 (verified) with the O-rescale pass skipped when max growth <= 11.5
// (log2 domain = 8 nats): P bounded by 2^11.5, f32 l and bf16 P tolerate it.
__global__ __launch_bounds__(512, 4) void k_attn(const u16* __restrict__ QKV,
                                                 const u16* __restrict__ Kr,
                                                 const u16* __restrict__ Vt,
                                                 const float2* __restrict__ tab,
                                                 const int* __restrict__ pos,
                                                 u16* __restrict__ ctx) {
  __shared__ __align__(16) u16 Ks[2][64 * 128];
  __shared__ __align__(16) u16 Vs[2][128 * 64];
  __shared__ __align__(16) u16 Ps[8][16 * 40];   // pitch 40 (80B): <=2-way banks
  const int bid = blockIdx.x;
  const int qt = 15 - (bid >> 6);          // longest-first
  const int bh = bid & 63;
  const int b = bh >> 5, h = bh & 31;
  const int kvh = h >> 2;
  const int tid = threadIdx.x;
  const int w = tid >> 6, lane = tid & 63;
  const int lrow = lane & 15, lk = lane >> 4;
  const int q0w = qt * 128 + w * 16;       // wave's first q row

  // ---- Q frags with RoPE fused (Q read once from qkvlin) ----
  const int s = q0w + lrow;
  const int p = pos[b * S_ + s];
  const u16* q0 = QKV + ((size_t)(b * S_ + s)) * NQKV_ + h * D_ + lk * 8;
  bf16x8 raw[4];
#pragma unroll
  for (int ks = 0; ks < 4; ++ks) raw[ks] = *(const bf16x8*)(q0 + ks * 32);
  bf16x8 qf[4];
#pragma unroll
  for (int ks = 0; ks < 2; ++ks)
#pragma unroll
    for (int e = 0; e < 8; ++e) {
      int d = ks * 32 + lk * 8 + e;
      float2 scv = tab[p * 64 + d];
      float x1 = bf2f((u16)raw[ks][e]), x2 = bf2f((u16)raw[ks + 2][e]);
      qf[ks][e]     = (short)f2bf(x1 * scv.y - x2 * scv.x);
      qf[ks + 2][e] = (short)f2bf(x2 * scv.y + x1 * scv.x);
    }

  float m[4] = {-1e30f, -1e30f, -1e30f, -1e30f};   // log2-domain running max
  float l[4] = {0.f, 0.f, 0.f, 0.f};
  f32x4 o[8] = {};

  const u16* kbase = Kr + (size_t)(b * KVH_ + kvh) * S_ * D_;
  const u16* vbase = Vt + (size_t)(b * KVH_ + kvh) * D_ * S_;
  const float cl = 0.12751743435f;  // (1/sqrt(128)) * log2(e)
  const int nt = 2 * qt + 2;

  auto STAGE = [&](int buf, int kb) {
    const int kv0 = kb << 6;
#pragma unroll
    for (int c = 0; c < 2; ++c) {          // K: 8 rows/wave, 4 rows/call
      int r = w * 8 + (lane >> 4) + c * 4;
      gload_lds16(kbase + (size_t)(kv0 + r) * D_ + (((lane & 15) ^ (r & 7)) << 3),
                  &Ks[buf][(w * 8 + c * 4) * 128]);
    }
#pragma unroll
    for (int c = 0; c < 2; ++c) {          // V^T: 16 rows/wave, 8 rows/call
      int r = w * 16 + (lane >> 3) + c * 8;
      gload_lds16(vbase + (size_t)r * S_ + kv0 + (((lane & 7) ^ (r & 7)) << 3),
                  &Vs[buf][(w * 16 + c * 8) * 64]);
    }
  };

  STAGE(0, 0);
  int cur = 0;
  for (int kb = 0; kb < nt; ++kb) {
    __syncthreads();                       // drains prev stage (vmcnt) + prev reads
    if (kb + 1 < nt) STAGE(cur ^ 1, kb + 1);
    const int kv0 = kb << 6;
    if (kv0 <= q0w + 15) {                 // wave-active tile
      const u16* Kb = &Ks[cur][0];
      const u16* Vb = &Vs[cur][0];

      // S = Q K^T (16 MFMAs)
      f32x4 sc[4] = {};
      __builtin_amdgcn_s_setprio(1);
#pragma unroll
      for (int n0 = 0; n0 < 4; ++n0) {
#pragma unroll
        for (int ks = 0; ks < 4; ++ks) {
          int krow = (n0 << 4) + lrow;
          bf16x8 kf = *(const bf16x8*)(Kb + krow * 128 + ((((ks << 2) + lk) ^ (krow & 7)) << 3));
          sc[n0] = __builtin_amdgcn_mfma_f32_16x16x32_bf16(qf[ks], kf, sc[n0], 0, 0, 0);
        }
      }
      __builtin_amdgcn_s_setprio(0);

      // scale (log2 domain) + causal mask (global indices) + online softmax
      const bool diag = (kv0 + 63 > q0w);
      float mnew[4] = {m[0], m[1], m[2], m[3]};
#pragma unroll
      for (int n0 = 0; n0 < 4; ++n0)
#pragma unroll
        for (int j = 0; j < 4; ++j) {
          float v = sc[n0][j] * cl;
          if (diag && (kv0 + (n0 << 4) + lrow > q0w + (lk << 2) + j)) v = -1e30f;
          sc[n0][j] = v;
          mnew[j] = fmaxf(mnew[j], v);
        }
#pragma unroll
      for (int j = 0; j < 4; ++j) {
        float v = mnew[j];
        v = fmaxf(v, __shfl_xor(v, 1));
        v = fmaxf(v, __shfl_xor(v, 2));
        v = fmaxf(v, __shfl_xor(v, 4));
        v = fmaxf(v, __shfl_xor(v, 8));
        mnew[j] = v;
      }

      // T13 defer-max: rescale only when max grew by > 11.5 (log2) anywhere
      bool need = false;
#pragma unroll
      for (int j = 0; j < 4; ++j) need |= (mnew[j] - m[j] > 11.5f);
      if (__any(need)) {
        float alpha[4];
#pragma unroll
        for (int j = 0; j < 4; ++j) {
          alpha[j] = exp2f(m[j] - mnew[j]);
          m[j] = mnew[j];
          l[j] *= alpha[j];
        }
#pragma unroll
        for (int db = 0; db < 8; ++db)
#pragma unroll
          for (int j = 0; j < 4; ++j)
            o[db][j] *= alpha[j];
      }

      float rs[4] = {0.f, 0.f, 0.f, 0.f};
#pragma unroll
      for (int n0 = 0; n0 < 4; ++n0)
#pragma unroll
        for (int j = 0; j < 4; ++j) {
          float pv = exp2f(sc[n0][j] - m[j]);
          sc[n0][j] = pv;
          rs[j] += pv;
        }
#pragma unroll
      for (int j = 0; j < 4; ++j) {
        float v = rs[j];
        v += __shfl_xor(v, 1); v += __shfl_xor(v, 2);
        v += __shfl_xor(v, 4); v += __shfl_xor(v, 8);
        l[j] += v;
      }

      // ---- O += P V in two kv-32 halves (Ps pitch 40, reused) ----
      u16* pw = &Ps[w][0];
#pragma unroll
      for (int half = 0; half < 2; ++half) {
        // WAR fence: prior pass's reads (and writes) drained before overwrite
        asm volatile("s_waitcnt lgkmcnt(0)" ::: "memory");
#pragma unroll
        for (int n0 = 0; n0 < 2; ++n0)
#pragma unroll
          for (int j = 0; j < 4; ++j)
            pw[((lk << 2) + j) * 40 + (n0 << 4) + lrow] =
                f2bf(sc[(half << 1) + n0][j]);
        bf16x8 pf = *(const bf16x8*)(pw + lrow * 40 + (lk << 3));
        __builtin_amdgcn_s_setprio(1);
#pragma unroll
        for (int db = 0; db < 8; ++db) {
          int dr = (db << 4) + lrow;
          bf16x8 vf = *(const bf16x8*)(Vb + dr * 64 + ((((half << 2) + lk) ^ (dr & 7)) << 3));
          o[db] = __builtin_amdgcn_mfma_f32_16x16x32_bf16(pf, vf, o[db], 0, 0, 0);
        }
        __builtin_amdgcn_s_setprio(0);
      }
    }
    cur ^= 1;
  }

#pragma unroll
  for (int j = 0; j < 4; ++j) l[j] = 1.0f / l[j];
#pragma unroll
  for (int db = 0; db < 8; ++db)
#pragma unroll
    for (int j = 0; j < 4; ++j) {
      int q = q0w + (lk << 2) + j;
      ctx[((size_t)(b * S_ + q)) * HD_ + h * D_ + (db << 4) + lrow] = f2bf(o[db][j] * l[j]);
    }
}

extern "C" void kernel_launch(void* const* d_in, const int* in_sizes, int n_in,
                              void* d_out, int out_size, void* d_ws, size_t ws_size,
                              hipStream_t stream) {
  const float* hidden = (const float*)d_in[0];
  const float* Wq = (const float*)d_in[1];
  const float* Wk = (const float*)d_in[2];
  const float* Wv = (const float*)d_in[3];
  const float* Wo = (const float*)d_in[4];
  const int* pos_ids = (const int*)d_in[7];

  char* ws = (char*)d_ws;
  u16* hs      = (u16*)(ws);                    // [0,32M)   hidden bf16; later ctx
  u16* ctx     = hs;                            //           ctx [B,S,H*D]
  u16* wqkvt   = (u16*)(ws + 33554432ull);      // [32,80M)  stacked [6144][4096]; later WoT
  u16* wot     = wqkvt;
  u16* qkvlin  = (u16*)(ws + 83886080ull);      // [80,128M) qkv_lin [M][6144]
  u16* kr      = (u16*)(ws + 134217728ull);     // [128,136M) k rope'd [B,KVH,S,D]
  u16* vt      = (u16*)(ws + 142606336ull);     // [136,144M) v^T [B,KVH,D,S]
  float2* tab  = (float2*)(ws + 150994944ull);  // [144,145M) sin/cos table

  // 1. hidden -> bf16
  k_f2bf<<<dim3((M_*E_)/1024), dim3(256), 0, stream>>>(hidden, hs, M_*E_);
  // 2. stacked W^T: rows [0,4096)=Wq^T, [4096,5120)=Wk^T, [5120,6144)=Wv^T
  k_transpose_f2bf<<<dim3(HD_/64, E_/64), dim3(256), 0, stream>>>(Wq, wqkvt, E_, HD_);
  k_transpose_f2bf<<<dim3(KVD_/64, E_/64), dim3(256), 0, stream>>>(Wk, wqkvt + (size_t)HD_*E_, E_, KVD_);
  k_transpose_f2bf<<<dim3(KVD_/64, E_/64), dim3(256), 0, stream>>>(Wv, wqkvt + (size_t)(HD_+KVD_)*E_, E_, KVD_);
  // 3. fused QKV projection: [M][6144]
  k_gemm_bt<false><<<dim3((M_/128)*(NQKV_/128)), dim3(256), 0, stream>>>(hs, wqkvt, (void*)qkvlin, M_, NQKV_, E_);
  // 4. Wo^T (reuses wqkvt region; QKV GEMM done)
  k_transpose_f2bf<<<dim3(E_/64, HD_/64), dim3(256), 0, stream>>>(Wo, wot, HD_, E_);
  // 5. sin/cos table
  k_table<<<dim3((S_*64)/256), dim3(256), 0, stream>>>(tab);
  // 6. RoPE K -> kr [B,KVH,S,D] (Q rope is fused into k_attn)
  k_rope<<<dim3((B_*KVH_*S_*64)/256), dim3(256), 0, stream>>>(qkvlin + HD_, kr, tab, pos_ids, KVH_, NQKV_, B_*KVH_*S_*64);
  // 7. V transpose -> [B,KVH,D,S]
  k_transpose_v<<<dim3(S_/64, D_/64, B_*KVH_), dim3(256), 0, stream>>>(qkvlin + HD_ + KVD_, vt, NQKV_);
  // 8. flash attention v9 -> ctx (hs region; hidden no longer needed)
  k_attn<<<dim3(B_*H_*(S_/128)), dim3(512), 0, stream>>>(qkvlin, kr, vt, tab, pos_ids, ctx);
  // 9. out = ctx @ Wo (fp32 epilogue)
  k_gemm_bt<true><<<dim3((M_/128)*(E_/128)), dim3(256), 0, stream>>>(ctx, wot, d_out, M_, E_, HD_);
}

// Round 12
// 587.386 us; speedup vs baseline: 1.2797x; 1.1427x over previous
//
#include <hip/hip_runtime.h>
#include <hip/hip_bf16.h>
#include <cstdint>
#include <cstddef>

#define B_ 2
#define S_ 2048
#define E_ 4096
#define H_ 32
#define KVH_ 8
#define D_ 128
#define M_ (B_*S_)      // 4096 rows (B*S)
#define HD_ (H_*D_)     // 4096
#define KVD_ (KVH_*D_)  // 1024
#define NQKV_ 6144      // HD_ + 2*KVD_

typedef unsigned short u16;
typedef __attribute__((ext_vector_type(8))) short bf16x8;
typedef __attribute__((ext_vector_type(4))) float f32x4;

__device__ __forceinline__ float bf2f(u16 u) {
  union { float f; uint32_t i; } v; v.i = ((uint32_t)u) << 16; return v.f;
}
__device__ __forceinline__ u16 f2bf(float f) {
  union { float f; uint32_t i; } v; v.f = f;
  uint32_t r = v.i + 0x7FFF + ((v.i >> 16) & 1);   // RNE
  return (u16)(r >> 16);
}

// async global->LDS, 16B per lane; LDS dest = wave-uniform base + lane*16
__device__ __forceinline__ void gload_lds16(const void* g, void* l) {
  __builtin_amdgcn_global_load_lds(
      (const __attribute__((address_space(1))) void*)g,
      (__attribute__((address_space(3))) void*)l, 16, 0, 0);
}

#define FENCE() asm volatile("" ::: "memory")
#define BARRIER() do { FENCE(); __builtin_amdgcn_s_barrier(); FENCE(); } while (0)
#define VMCNT6() asm volatile("s_waitcnt vmcnt(6)" ::: "memory")

// ---------------- elementwise f32 -> bf16 ----------------
__global__ __launch_bounds__(256) void k_f2bf(const float* __restrict__ in,
                                              u16* __restrict__ out, int n) {
  int i = (blockIdx.x * 256 + threadIdx.x) * 4;
  if (i + 3 < n) {
    float4 v = *(const float4*)(in + i);
    *(ushort4*)(out + i) = make_ushort4(f2bf(v.x), f2bf(v.y), f2bf(v.z), f2bf(v.w));
  }
}

// ------- transpose-convert f32 [R][C] -> bf16 [C][R], 64x64, ushort2 stores ----
__global__ __launch_bounds__(256) void k_transpose_f2bf(const float* __restrict__ in,
                                                        u16* __restrict__ out, int R, int C) {
  __shared__ float tile[64][65];
  const int c0 = blockIdx.x * 64, r0 = blockIdx.y * 64;
  const int tid = threadIdx.x;
  const int lx = tid & 63, ty = tid >> 6;        // loads: 64-lane rows
#pragma unroll
  for (int i = 0; i < 16; ++i)
    tile[ty + 4 * i][lx] = in[(size_t)(r0 + ty + 4 * i) * C + c0 + lx];
  __syncthreads();
  const int oy = tid & 31, xb = tid >> 5;        // stores: 32 lanes x ushort2 = 128B
#pragma unroll
  for (int i = 0; i < 8; ++i) {
    int X = xb + 8 * i;
    *(ushort2*)(out + (size_t)(c0 + X) * R + r0 + 2 * oy) =
        make_ushort2(f2bf(tile[2 * oy][X]), f2bf(tile[2 * oy + 1][X]));
  }
}

// -- transpose v cols of qkvlin -> vt [B][KVH][D][S] (bf16), 64x64 vectorized --
__global__ __launch_bounds__(256) void k_transpose_v(const u16* __restrict__ vlin,
                                                     u16* __restrict__ vt, int stride) {
  __shared__ u16 tile[64][65];
  const int bk = blockIdx.z;             // b*KVH + kvh
  const int b = bk >> 3, kvh = bk & 7;
  const int s0 = blockIdx.x * 64, d0 = blockIdx.y * 64;
  const int tid = threadIdx.x;
  const int lx = tid & 63, ty = tid >> 6;
#pragma unroll
  for (int i = 0; i < 16; ++i)
    tile[ty + 4 * i][lx] =
        vlin[(size_t)(b * S_ + s0 + ty + 4 * i) * stride + kvh * D_ + d0 + lx];
  __syncthreads();
  const int oy = tid & 31, xb = tid >> 5;
#pragma unroll
  for (int i = 0; i < 8; ++i) {
    int X = xb + 8 * i;
    *(ushort2*)(vt + ((size_t)bk * D_ + d0 + X) * S_ + s0 + 2 * oy) =
        make_ushort2(tile[2 * oy][X], tile[2 * oy + 1][X]);
  }
}

// ---------------- RoPE sin/cos table [S][64] ----------------
__global__ __launch_bounds__(256) void k_table(float2* __restrict__ tab) {
  int i = blockIdx.x * 256 + threadIdx.x;
  if (i < S_ * 64) {
    int s = i >> 6, d = i & 63;
    float inv = powf(10000.0f, -(float)d / 64.0f);
    float f = (float)s * inv;
    tab[i] = make_float2(sinf(f), cosf(f));
  }
}

// -------- RoPE + head reorder: strided cols of [B,S,*] -> [B,heads,S,D] --------
__global__ __launch_bounds__(256) void k_rope(const u16* __restrict__ in, u16* __restrict__ out,
                                              const float2* __restrict__ tab,
                                              const int* __restrict__ pos,
                                              int heads, int in_stride, int total) {
  int i = blockIdx.x * 256 + threadIdx.x;
  if (i >= total) return;
  int d = i & 63;
  int s = (i >> 6) & (S_ - 1);
  int bh = i >> 17;                 // 64*S_ = 2^17
  int h = bh % heads, b = bh / heads;
  size_t ibase = ((size_t)(b * S_ + s)) * in_stride + h * D_;
  float2 scv = tab[pos[b * S_ + s] * 64 + d];
  float x1 = bf2f(in[ibase + d]), x2 = bf2f(in[ibase + d + 64]);
  size_t obase = ((size_t)bh * S_ + s) * D_;
  out[obase + d]      = f2bf(x1 * scv.y - x2 * scv.x);
  out[obase + d + 64] = f2bf(x2 * scv.y + x1 * scv.x);
}

// ---------------- bf16 GEMM v5: 8-phase 256x256, counted vmcnt(6) ----------------
// C[M,N] = A[M,K]*BT[N,K]^T. 8 waves (2Mx4N), per-wave 128x64, 16x16x32 MFMA
// (r1/r5-verified frag+C/D path). LDS 128KB: 2 buf x {A-half0,A-half1,B-half0,
// B-half1} of [128][64] (16KB each), XOR-swizzled (verified involution).
// Iteration = 2 K-tiles (even in buf0, odd in buf1), 8 phases, 1 half-tile
// staged/phase, 16 MFMA/phase, vmcnt(6) ONLY at p0/p4 (retires exactly the
// half-tiles consumed next; 3 half-tiles stay in flight across barriers).
// Stage slots: p0:YA0(t+1) p1:YA1 p2:XB0(t+2) p3:XB1 p4:XA0(t+2) p5:XA1
// p6:YB0(t+3) p7:YB1. Min stage->consume distance = 4 phases.
template<bool OUTF32>
__global__ __launch_bounds__(512, 2) void k_gemm8(const u16* __restrict__ A,
                                                  const u16* __restrict__ BT,
                                                  void* __restrict__ Cp,
                                                  int M, int N, int K) {
  __shared__ __align__(16) u16 L[8 * 8192];  // [buf][mat][half][128*64]
  const int tid = threadIdx.x;
  const int w = tid >> 6, lane = tid & 63;
  const int lrow = lane & 15, lk = lane >> 4;
  const int nbn = N >> 8;
  const int tm = blockIdx.x / nbn, tn = blockIdx.x % nbn;
  const int m0 = tm << 8, n0 = tn << 8;
  const int wm = w >> 2, wn = w & 3;

  f32x4 acc[8][4] = {};
  bf16x8 bres[4][2];
  const int nt = K >> 6;

  const u16* RA[2] = { &L[(0 + wm) * 8192],       &L[(4 + wm) * 8192] };
  const u16* RB[2] = { &L[(2 + (wn >> 1)) * 8192], &L[(6 + (wn >> 1)) * 8192] };

  auto STAGE = [&](int buf, int mat, int half, int t) {
    const u16* src = mat ? BT : A;
    const int base0 = mat ? n0 : m0;
    u16* reg = &L[(buf * 4 + mat * 2 + half) * 8192];
#pragma unroll
    for (int c = 0; c < 2; ++c) {
      int rl = (c << 6) + (w << 3) + (lane >> 3);
      int gb = (lane & 7) ^ (rl & 7);
      gload_lds16(src + (size_t)(base0 + (half << 7) + rl) * K + (t << 6) + (gb << 3),
                  reg + ((c << 6) + (w << 3)) * 64);
    }
  };
  auto LDB = [&](int buf) {
#pragma unroll
    for (int nf = 0; nf < 4; ++nf)
#pragma unroll
      for (int ks = 0; ks < 2; ++ks) {
        int br = ((wn & 1) << 6) + (nf << 4) + lrow;
        int cb = (ks << 2) + lk;
        bres[nf][ks] = *(const bf16x8*)(RB[buf] + br * 64 + ((cb ^ (br & 7)) << 3));
      }
  };
  auto LDA2 = [&](int buf, int mp, bf16x8 (&af)[2][2]) {
#pragma unroll
    for (int d = 0; d < 2; ++d)
#pragma unroll
      for (int ks = 0; ks < 2; ++ks) {
        int ar = (((mp << 1) + d) << 4) + lrow;
        int cb = (ks << 2) + lk;
        af[d][ks] = *(const bf16x8*)(RA[buf] + ar * 64 + ((cb ^ (ar & 7)) << 3));
      }
  };
  auto MM2 = [&](int mp, bf16x8 (&af)[2][2]) {
    __builtin_amdgcn_s_setprio(1);
#pragma unroll
    for (int ks = 0; ks < 2; ++ks)
#pragma unroll
      for (int d = 0; d < 2; ++d)
#pragma unroll
        for (int nf = 0; nf < 4; ++nf)
          acc[(mp << 1) + d][nf] = __builtin_amdgcn_mfma_f32_16x16x32_bf16(
              af[d][ks], bres[nf][ks], acc[(mp << 1) + d][nf], 0, 0, 0);
    __builtin_amdgcn_s_setprio(0);
  };

  // prologue: X.B0,X.B1,X.A0,X.A1 (tile 0), Y.B0,Y.B1 (tile 1) — 12 loads
  STAGE(0, 1, 0, 0); STAGE(0, 1, 1, 0);
  STAGE(0, 0, 0, 0); STAGE(0, 0, 1, 0);
  STAGE(1, 1, 0, 1); STAGE(1, 1, 1, 1);

  const int niter = nt >> 1;
  for (int i = 0; i < niter; ++i) {
    const int t1 = 2 * i + 1;
    const int t2 = (2 * i + 2 < nt) ? 2 * i + 2 : nt - 1;
    const int t3 = (2 * i + 3 < nt) ? 2 * i + 3 : nt - 1;
    bf16x8 afA[2][2], afB[2][2];

    // ---- K-tile 2i from buf0 ----
    STAGE(1, 0, 0, t1);                 // p0: Y.A0
    VMCNT6();                           // X.{A,B}(2i) landed
    BARRIER();
    LDB(0); LDA2(0, 0, afA);
    MM2(0, afA);
    LDA2(0, 1, afB);
    BARRIER();
    STAGE(1, 0, 1, t1);                 // p1: Y.A1
    MM2(1, afB);
    LDA2(0, 2, afA);
    BARRIER();
    STAGE(0, 1, 0, t2);                 // p2: X.B0
    MM2(2, afA);
    LDA2(0, 3, afB);
    BARRIER();
    STAGE(0, 1, 1, t2);                 // p3: X.B1
    MM2(3, afB);
    BARRIER();

    // ---- K-tile 2i+1 from buf1 ----
    STAGE(0, 0, 0, t2);                 // p4: X.A0
    VMCNT6();                           // Y.{A,B}(2i+1) landed
    BARRIER();
    LDB(1); LDA2(1, 0, afA);
    MM2(0, afA);
    LDA2(1, 1, afB);
    BARRIER();
    STAGE(0, 0, 1, t2);                 // p5: X.A1
    MM2(1, afB);
    LDA2(1, 2, afA);
    BARRIER();
    STAGE(1, 1, 0, t3);                 // p6: Y.B0
    MM2(2, afA);
    LDA2(1, 3, afB);
    BARRIER();
    STAGE(1, 1, 1, t3);                 // p7: Y.B1
    MM2(3, afB);
    BARRIER();
  }

  // epilogue: r1-verified 16x16 C/D mapping
#pragma unroll
  for (int mi = 0; mi < 8; ++mi)
#pragma unroll
    for (int nf = 0; nf < 4; ++nf) {
      int col = n0 + (wn << 6) + (nf << 4) + lrow;
#pragma unroll
      for (int j = 0; j < 4; ++j) {
        int row = m0 + (wm << 7) + (mi << 4) + (lk << 2) + j;
        if (OUTF32) ((float*)Cp)[(size_t)row * N + col] = acc[mi][nf][j];
        else        ((u16*)Cp)[(size_t)row * N + col]  = f2bf(acc[mi][nf][j]);
      }
    }
}

// ---------------- flash attention v9 (unchanged from round 11 — verified) ----
__global__ __launch_bounds__(512, 4) void k_attn(const u16* __restrict__ QKV,
                                                 const u16* __restrict__ Kr,
                                                 const u16* __restrict__ Vt,
                                                 const float2* __restrict__ tab,
                                                 const int* __restrict__ pos,
                                                 u16* __restrict__ ctx) {
  __shared__ __align__(16) u16 Ks[2][64 * 128];
  __shared__ __align__(16) u16 Vs[2][128 * 64];
  __shared__ __align__(16) u16 Ps[8][16 * 40];   // pitch 40 (80B): <=2-way banks
  const int bid = blockIdx.x;
  const int qt = 15 - (bid >> 6);          // longest-first
  const int bh = bid & 63;
  const int b = bh >> 5, h = bh & 31;
  const int kvh = h >> 2;
  const int tid = threadIdx.x;
  const int w = tid >> 6, lane = tid & 63;
  const int lrow = lane & 15, lk = lane >> 4;
  const int q0w = qt * 128 + w * 16;       // wave's first q row

  // ---- Q frags with RoPE fused (Q read once from qkvlin) ----
  const int s = q0w + lrow;
  const int p = pos[b * S_ + s];
  const u16* q0 = QKV + ((size_t)(b * S_ + s)) * NQKV_ + h * D_ + lk * 8;
  bf16x8 raw[4];
#pragma unroll
  for (int ks = 0; ks < 4; ++ks) raw[ks] = *(const bf16x8*)(q0 + ks * 32);
  bf16x8 qf[4];
#pragma unroll
  for (int ks = 0; ks < 2; ++ks)
#pragma unroll
    for (int e = 0; e < 8; ++e) {
      int d = ks * 32 + lk * 8 + e;
      float2 scv = tab[p * 64 + d];
      float x1 = bf2f((u16)raw[ks][e]), x2 = bf2f((u16)raw[ks + 2][e]);
      qf[ks][e]     = (short)f2bf(x1 * scv.y - x2 * scv.x);
      qf[ks + 2][e] = (short)f2bf(x2 * scv.y + x1 * scv.x);
    }

  float m[4] = {-1e30f, -1e30f, -1e30f, -1e30f};   // log2-domain running max
  float l[4] = {0.f, 0.f, 0.f, 0.f};
  f32x4 o[8] = {};

  const u16* kbase = Kr + (size_t)(b * KVH_ + kvh) * S_ * D_;
  const u16* vbase = Vt + (size_t)(b * KVH_ + kvh) * D_ * S_;
  const float cl = 0.12751743435f;  // (1/sqrt(128)) * log2(e)
  const int nt = 2 * qt + 2;

  auto STAGE = [&](int buf, int kb) {
    const int kv0 = kb << 6;
#pragma unroll
    for (int c = 0; c < 2; ++c) {          // K: 8 rows/wave, 4 rows/call
      int r = w * 8 + (lane >> 4) + c * 4;
      gload_lds16(kbase + (size_t)(kv0 + r) * D_ + (((lane & 15) ^ (r & 7)) << 3),
                  &Ks[buf][(w * 8 + c * 4) * 128]);
    }
#pragma unroll
    for (int c = 0; c < 2; ++c) {          // V^T: 16 rows/wave, 8 rows/call
      int r = w * 16 + (lane >> 3) + c * 8;
      gload_lds16(vbase + (size_t)r * S_ + kv0 + (((lane & 7) ^ (r & 7)) << 3),
                  &Vs[buf][(w * 16 + c * 8) * 64]);
    }
  };

  STAGE(0, 0);
  int cur = 0;
  for (int kb = 0; kb < nt; ++kb) {
    __syncthreads();                       // drains prev stage (vmcnt) + prev reads
    if (kb + 1 < nt) STAGE(cur ^ 1, kb + 1);
    const int kv0 = kb << 6;
    if (kv0 <= q0w + 15) {                 // wave-active tile
      const u16* Kb = &Ks[cur][0];
      const u16* Vb = &Vs[cur][0];

      // S = Q K^T (16 MFMAs)
      f32x4 sc[4] = {};
      __builtin_amdgcn_s_setprio(1);
#pragma unroll
      for (int n0 = 0; n0 < 4; ++n0) {
#pragma unroll
        for (int ks = 0; ks < 4; ++ks) {
          int krow = (n0 << 4) + lrow;
          bf16x8 kf = *(const bf16x8*)(Kb + krow * 128 + ((((ks << 2) + lk) ^ (krow & 7)) << 3));
          sc[n0] = __builtin_amdgcn_mfma_f32_16x16x32_bf16(qf[ks], kf, sc[n0], 0, 0, 0);
        }
      }
      __builtin_amdgcn_s_setprio(0);

      // scale (log2 domain) + causal mask (global indices) + online softmax
      const bool diag = (kv0 + 63 > q0w);
      float mnew[4] = {m[0], m[1], m[2], m[3]};
#pragma unroll
      for (int n0 = 0; n0 < 4; ++n0)
#pragma unroll
        for (int j = 0; j < 4; ++j) {
          float v = sc[n0][j] * cl;
          if (diag && (kv0 + (n0 << 4) + lrow > q0w + (lk << 2) + j)) v = -1e30f;
          sc[n0][j] = v;
          mnew[j] = fmaxf(mnew[j], v);
        }
#pragma unroll
      for (int j = 0; j < 4; ++j) {
        float v = mnew[j];
        v = fmaxf(v, __shfl_xor(v, 1));
        v = fmaxf(v, __shfl_xor(v, 2));
        v = fmaxf(v, __shfl_xor(v, 4));
        v = fmaxf(v, __shfl_xor(v, 8));
        mnew[j] = v;
      }

      // T13 defer-max: rescale only when max grew by > 11.5 (log2) anywhere
      bool need = false;
#pragma unroll
      for (int j = 0; j < 4; ++j) need |= (mnew[j] - m[j] > 11.5f);
      if (__any(need)) {
        float alpha[4];
#pragma unroll
        for (int j = 0; j < 4; ++j) {
          alpha[j] = exp2f(m[j] - mnew[j]);
          m[j] = mnew[j];
          l[j] *= alpha[j];
        }
#pragma unroll
        for (int db = 0; db < 8; ++db)
#pragma unroll
          for (int j = 0; j < 4; ++j)
            o[db][j] *= alpha[j];
      }

      float rs[4] = {0.f, 0.f, 0.f, 0.f};
#pragma unroll
      for (int n0 = 0; n0 < 4; ++n0)
#pragma unroll
        for (int j = 0; j < 4; ++j) {
          float pv = exp2f(sc[n0][j] - m[j]);
          sc[n0][j] = pv;
          rs[j] += pv;
        }
#pragma unroll
      for (int j = 0; j < 4; ++j) {
        float v = rs[j];
        v += __shfl_xor(v, 1); v += __shfl_xor(v, 2);
        v += __shfl_xor(v, 4); v += __shfl_xor(v, 8);
        l[j] += v;
      }

      // ---- O += P V in two kv-32 halves (Ps pitch 40, reused) ----
      u16* pw = &Ps[w][0];
#pragma unroll
      for (int half = 0; half < 2; ++half) {
        // WAR fence: prior pass's reads (and writes) drained before overwrite
        asm volatile("s_waitcnt lgkmcnt(0)" ::: "memory");
#pragma unroll
        for (int n0 = 0; n0 < 2; ++n0)
#pragma unroll
          for (int j = 0; j < 4; ++j)
            pw[((lk << 2) + j) * 40 + (n0 << 4) + lrow] =
                f2bf(sc[(half << 1) + n0][j]);
        bf16x8 pf = *(const bf16x8*)(pw + lrow * 40 + (lk << 3));
        __builtin_amdgcn_s_setprio(1);
#pragma unroll
        for (int db = 0; db < 8; ++db) {
          int dr = (db << 4) + lrow;
          bf16x8 vf = *(const bf16x8*)(Vb + dr * 64 + ((((half << 2) + lk) ^ (dr & 7)) << 3));
          o[db] = __builtin_amdgcn_mfma_f32_16x16x32_bf16(pf, vf, o[db], 0, 0, 0);
        }
        __builtin_amdgcn_s_setprio(0);
      }
    }
    cur ^= 1;
  }

#pragma unroll
  for (int j = 0; j < 4; ++j) l[j] = 1.0f / l[j];
#pragma unroll
  for (int db = 0; db < 8; ++db)
#pragma unroll
    for (int j = 0; j < 4; ++j) {
      int q = q0w + (lk << 2) + j;
      ctx[((size_t)(b * S_ + q)) * HD_ + h * D_ + (db << 4) + lrow] = f2bf(o[db][j] * l[j]);
    }
}

extern "C" void kernel_launch(void* const* d_in, const int* in_sizes, int n_in,
                              void* d_out, int out_size, void* d_ws, size_t ws_size,
                              hipStream_t stream) {
  const float* hidden = (const float*)d_in[0];
  const float* Wq = (const float*)d_in[1];
  const float* Wk = (const float*)d_in[2];
  const float* Wv = (const float*)d_in[3];
  const float* Wo = (const float*)d_in[4];
  const int* pos_ids = (const int*)d_in[7];

  char* ws = (char*)d_ws;
  u16* hs      = (u16*)(ws);                    // [0,32M)   hidden bf16; later ctx
  u16* ctx     = hs;                            //           ctx [B,S,H*D]
  u16* wqkvt   = (u16*)(ws + 33554432ull);      // [32,80M)  stacked [6144][4096]; later WoT
  u16* wot     = wqkvt;
  u16* qkvlin  = (u16*)(ws + 83886080ull);      // [80,128M) qkv_lin [M][6144]
  u16* kr      = (u16*)(ws + 134217728ull);     // [128,136M) k rope'd [B,KVH,S,D]
  u16* vt      = (u16*)(ws + 142606336ull);     // [136,144M) v^T [B,KVH,D,S]
  float2* tab  = (float2*)(ws + 150994944ull);  // [144,145M) sin/cos table

  // 1. hidden -> bf16
  k_f2bf<<<dim3((M_*E_)/1024), dim3(256), 0, stream>>>(hidden, hs, M_*E_);
  // 2. stacked W^T: rows [0,4096)=Wq^T, [4096,5120)=Wk^T, [5120,6144)=Wv^T
  k_transpose_f2bf<<<dim3(HD_/64, E_/64), dim3(256), 0, stream>>>(Wq, wqkvt, E_, HD_);
  k_transpose_f2bf<<<dim3(KVD_/64, E_/64), dim3(256), 0, stream>>>(Wk, wqkvt + (size_t)HD_*E_, E_, KVD_);
  k_transpose_f2bf<<<dim3(KVD_/64, E_/64), dim3(256), 0, stream>>>(Wv, wqkvt + (size_t)(HD_+KVD_)*E_, E_, KVD_);
  // 3. fused QKV projection: [M][6144], 256^2 8-phase
  k_gemm8<false><<<dim3((M_/256)*(NQKV_/256)), dim3(512), 0, stream>>>(hs, wqkvt, (void*)qkvlin, M_, NQKV_, E_);
  // 4. Wo^T (reuses wqkvt region; QKV GEMM done)
  k_transpose_f2bf<<<dim3(E_/64, HD_/64), dim3(256), 0, stream>>>(Wo, wot, HD_, E_);
  // 5. sin/cos table
  k_table<<<dim3((S_*64)/256), dim3(256), 0, stream>>>(tab);
  // 6. RoPE K -> kr [B,KVH,S,D] (Q rope is fused into k_attn)
  k_rope<<<dim3((B_*KVH_*S_*64)/256), dim3(256), 0, stream>>>(qkvlin + HD_, kr, tab, pos_ids, KVH_, NQKV_, B_*KVH_*S_*64);
  // 7. V transpose -> [B,KVH,D,S]
  k_transpose_v<<<dim3(S_/64, D_/64, B_*KVH_), dim3(256), 0, stream>>>(qkvlin + HD_ + KVD_, vt, NQKV_);
  // 8. flash attention v9 -> ctx (hs region; hidden no longer needed)
  k_attn<<<dim3(B_*H_*(S_/128)), dim3(512), 0, stream>>>(qkvlin, kr, vt, tab, pos_ids, ctx);
  // 9. out = ctx @ Wo (fp32 epilogue), 256^2 8-phase
  k_gemm8<true><<<dim3((M_/256)*(E_/256)), dim3(512), 0, stream>>>(ctx, wot, d_out, M_, E_, HD_);
}

// Round 14
// 587.164 us; speedup vs baseline: 1.2802x; 1.0004x over previous
//
#include <hip/hip_runtime.h>
#include <hip/hip_bf16.h>
#include <cstdint>
#include <cstddef>

#define B_ 2
#define S_ 2048
#define E_ 4096
#define H_ 32
#define KVH_ 8
#define D_ 128
#define M_ (B_*S_)      // 4096 rows (B*S)
#define HD_ (H_*D_)     // 4096
#define KVD_ (KVH_*D_)  // 1024
#define NQKV_ 6144      // HD_ + 2*KVD_

typedef unsigned short u16;
typedef __attribute__((ext_vector_type(8))) short bf16x8;
typedef __attribute__((ext_vector_type(4))) float f32x4;

__device__ __forceinline__ float bf2f(u16 u) {
  union { float f; uint32_t i; } v; v.i = ((uint32_t)u) << 16; return v.f;
}
__device__ __forceinline__ u16 f2bf(float f) {
  union { float f; uint32_t i; } v; v.f = f;
  uint32_t r = v.i + 0x7FFF + ((v.i >> 16) & 1);   // RNE
  return (u16)(r >> 16);
}

// async global->LDS, 16B per lane; LDS dest = wave-uniform base + lane*16
__device__ __forceinline__ void gload_lds16(const void* g, void* l) {
  __builtin_amdgcn_global_load_lds(
      (const __attribute__((address_space(1))) void*)g,
      (__attribute__((address_space(3))) void*)l, 16, 0, 0);
}

#define FENCE() asm volatile("" ::: "memory")
#define BARRIER() do { FENCE(); __builtin_amdgcn_s_barrier(); FENCE(); } while (0)
#define VMCNT6() asm volatile("s_waitcnt vmcnt(6)" ::: "memory")

// ---------------- elementwise f32 -> bf16 ----------------
__global__ __launch_bounds__(256) void k_f2bf(const float* __restrict__ in,
                                              u16* __restrict__ out, int n) {
  int i = (blockIdx.x * 256 + threadIdx.x) * 4;
  if (i + 3 < n) {
    float4 v = *(const float4*)(in + i);
    *(ushort4*)(out + i) = make_ushort4(f2bf(v.x), f2bf(v.y), f2bf(v.z), f2bf(v.w));
  }
}

// ------- transpose-convert f32 [R][C] -> bf16 [C][R], 64x64, ushort2 stores ----
__global__ __launch_bounds__(256) void k_transpose_f2bf(const float* __restrict__ in,
                                                        u16* __restrict__ out, int R, int C) {
  __shared__ float tile[64][65];
  const int c0 = blockIdx.x * 64, r0 = blockIdx.y * 64;
  const int tid = threadIdx.x;
  const int lx = tid & 63, ty = tid >> 6;        // loads: 64-lane rows
#pragma unroll
  for (int i = 0; i < 16; ++i)
    tile[ty + 4 * i][lx] = in[(size_t)(r0 + ty + 4 * i) * C + c0 + lx];
  __syncthreads();
  const int oy = tid & 31, xb = tid >> 5;        // stores: 32 lanes x ushort2 = 128B
#pragma unroll
  for (int i = 0; i < 8; ++i) {
    int X = xb + 8 * i;
    *(ushort2*)(out + (size_t)(c0 + X) * R + r0 + 2 * oy) =
        make_ushort2(f2bf(tile[2 * oy][X]), f2bf(tile[2 * oy + 1][X]));
  }
}

// -- transpose v cols of qkvlin -> vt [B][KVH][D][S] (bf16), 64x64 vectorized --
__global__ __launch_bounds__(256) void k_transpose_v(const u16* __restrict__ vlin,
                                                     u16* __restrict__ vt, int stride) {
  __shared__ u16 tile[64][65];
  const int bk = blockIdx.z;             // b*KVH + kvh
  const int b = bk >> 3, kvh = bk & 7;
  const int s0 = blockIdx.x * 64, d0 = blockIdx.y * 64;
  const int tid = threadIdx.x;
  const int lx = tid & 63, ty = tid >> 6;
#pragma unroll
  for (int i = 0; i < 16; ++i)
    tile[ty + 4 * i][lx] =
        vlin[(size_t)(b * S_ + s0 + ty + 4 * i) * stride + kvh * D_ + d0 + lx];
  __syncthreads();
  const int oy = tid & 31, xb = tid >> 5;
#pragma unroll
  for (int i = 0; i < 8; ++i) {
    int X = xb + 8 * i;
    *(ushort2*)(vt + ((size_t)bk * D_ + d0 + X) * S_ + s0 + 2 * oy) =
        make_ushort2(tile[2 * oy][X], tile[2 * oy + 1][X]);
  }
}

// ---------------- RoPE sin/cos table [S][64] ----------------
__global__ __launch_bounds__(256) void k_table(float2* __restrict__ tab) {
  int i = blockIdx.x * 256 + threadIdx.x;
  if (i < S_ * 64) {
    int s = i >> 6, d = i & 63;
    float inv = powf(10000.0f, -(float)d / 64.0f);
    float f = (float)s * inv;
    tab[i] = make_float2(sinf(f), cosf(f));
  }
}

// -------- RoPE + head reorder: strided cols of [B,S,*] -> [B,heads,S,D] --------
__global__ __launch_bounds__(256) void k_rope(const u16* __restrict__ in, u16* __restrict__ out,
                                              const float2* __restrict__ tab,
                                              const int* __restrict__ pos,
                                              int heads, int in_stride, int total) {
  int i = blockIdx.x * 256 + threadIdx.x;
  if (i >= total) return;
  int d = i & 63;
  int s = (i >> 6) & (S_ - 1);
  int bh = i >> 17;                 // 64*S_ = 2^17
  int h = bh % heads, b = bh / heads;
  size_t ibase = ((size_t)(b * S_ + s)) * in_stride + h * D_;
  float2 scv = tab[pos[b * S_ + s] * 64 + d];
  float x1 = bf2f(in[ibase + d]), x2 = bf2f(in[ibase + d + 64]);
  size_t obase = ((size_t)bh * S_ + s) * D_;
  out[obase + d]      = f2bf(x1 * scv.y - x2 * scv.x);
  out[obase + d + 64] = f2bf(x2 * scv.y + x1 * scv.x);
}

// ---------------- bf16 GEMM v5: 8-phase 256x256, counted vmcnt(6) ----------------
// (unchanged from round 12 — verified, 952 TF, 0 bank conflicts)
template<bool OUTF32>
__global__ __launch_bounds__(512, 2) void k_gemm8(const u16* __restrict__ A,
                                                  const u16* __restrict__ BT,
                                                  void* __restrict__ Cp,
                                                  int M, int N, int K) {
  __shared__ __align__(16) u16 L[8 * 8192];  // [buf][mat][half][128*64]
  const int tid = threadIdx.x;
  const int w = tid >> 6, lane = tid & 63;
  const int lrow = lane & 15, lk = lane >> 4;
  const int nbn = N >> 8;
  const int tm = blockIdx.x / nbn, tn = blockIdx.x % nbn;
  const int m0 = tm << 8, n0 = tn << 8;
  const int wm = w >> 2, wn = w & 3;

  f32x4 acc[8][4] = {};
  bf16x8 bres[4][2];
  const int nt = K >> 6;

  const u16* RA[2] = { &L[(0 + wm) * 8192],       &L[(4 + wm) * 8192] };
  const u16* RB[2] = { &L[(2 + (wn >> 1)) * 8192], &L[(6 + (wn >> 1)) * 8192] };

  auto STAGE = [&](int buf, int mat, int half, int t) {
    const u16* src = mat ? BT : A;
    const int base0 = mat ? n0 : m0;
    u16* reg = &L[(buf * 4 + mat * 2 + half) * 8192];
#pragma unroll
    for (int c = 0; c < 2; ++c) {
      int rl = (c << 6) + (w << 3) + (lane >> 3);
      int gb = (lane & 7) ^ (rl & 7);
      gload_lds16(src + (size_t)(base0 + (half << 7) + rl) * K + (t << 6) + (gb << 3),
                  reg + ((c << 6) + (w << 3)) * 64);
    }
  };
  auto LDB = [&](int buf) {
#pragma unroll
    for (int nf = 0; nf < 4; ++nf)
#pragma unroll
      for (int ks = 0; ks < 2; ++ks) {
        int br = ((wn & 1) << 6) + (nf << 4) + lrow;
        int cb = (ks << 2) + lk;
        bres[nf][ks] = *(const bf16x8*)(RB[buf] + br * 64 + ((cb ^ (br & 7)) << 3));
      }
  };
  auto LDA2 = [&](int buf, int mp, bf16x8 (&af)[2][2]) {
#pragma unroll
    for (int d = 0; d < 2; ++d)
#pragma unroll
      for (int ks = 0; ks < 2; ++ks) {
        int ar = (((mp << 1) + d) << 4) + lrow;
        int cb = (ks << 2) + lk;
        af[d][ks] = *(const bf16x8*)(RA[buf] + ar * 64 + ((cb ^ (ar & 7)) << 3));
      }
  };
  auto MM2 = [&](int mp, bf16x8 (&af)[2][2]) {
    __builtin_amdgcn_s_setprio(1);
#pragma unroll
    for (int ks = 0; ks < 2; ++ks)
#pragma unroll
      for (int d = 0; d < 2; ++d)
#pragma unroll
        for (int nf = 0; nf < 4; ++nf)
          acc[(mp << 1) + d][nf] = __builtin_amdgcn_mfma_f32_16x16x32_bf16(
              af[d][ks], bres[nf][ks], acc[(mp << 1) + d][nf], 0, 0, 0);
    __builtin_amdgcn_s_setprio(0);
  };

  // prologue: X.B0,X.B1,X.A0,X.A1 (tile 0), Y.B0,Y.B1 (tile 1) — 12 loads
  STAGE(0, 1, 0, 0); STAGE(0, 1, 1, 0);
  STAGE(0, 0, 0, 0); STAGE(0, 0, 1, 0);
  STAGE(1, 1, 0, 1); STAGE(1, 1, 1, 1);

  const int niter = nt >> 1;
  for (int i = 0; i < niter; ++i) {
    const int t1 = 2 * i + 1;
    const int t2 = (2 * i + 2 < nt) ? 2 * i + 2 : nt - 1;
    const int t3 = (2 * i + 3 < nt) ? 2 * i + 3 : nt - 1;
    bf16x8 afA[2][2], afB[2][2];

    // ---- K-tile 2i from buf0 ----
    STAGE(1, 0, 0, t1);                 // p0: Y.A0
    VMCNT6();                           // X.{A,B}(2i) landed
    BARRIER();
    LDB(0); LDA2(0, 0, afA);
    MM2(0, afA);
    LDA2(0, 1, afB);
    BARRIER();
    STAGE(1, 0, 1, t1);                 // p1: Y.A1
    MM2(1, afB);
    LDA2(0, 2, afA);
    BARRIER();
    STAGE(0, 1, 0, t2);                 // p2: X.B0
    MM2(2, afA);
    LDA2(0, 3, afB);
    BARRIER();
    STAGE(0, 1, 1, t2);                 // p3: X.B1
    MM2(3, afB);
    BARRIER();

    // ---- K-tile 2i+1 from buf1 ----
    STAGE(0, 0, 0, t2);                 // p4: X.A0
    VMCNT6();                           // Y.{A,B}(2i+1) landed
    BARRIER();
    LDB(1); LDA2(1, 0, afA);
    MM2(0, afA);
    LDA2(1, 1, afB);
    BARRIER();
    STAGE(0, 0, 1, t2);                 // p5: X.A1
    MM2(1, afB);
    LDA2(1, 2, afA);
    BARRIER();
    STAGE(1, 1, 0, t3);                 // p6: Y.B0
    MM2(2, afA);
    LDA2(1, 3, afB);
    BARRIER();
    STAGE(1, 1, 1, t3);                 // p7: Y.B1
    MM2(3, afB);
    BARRIER();
  }

  // epilogue: r1-verified 16x16 C/D mapping
#pragma unroll
  for (int mi = 0; mi < 8; ++mi)
#pragma unroll
    for (int nf = 0; nf < 4; ++nf) {
      int col = n0 + (wn << 6) + (nf << 4) + lrow;
#pragma unroll
      for (int j = 0; j < 4; ++j) {
        int row = m0 + (wm << 7) + (mi << 4) + (lk << 2) + j;
        if (OUTF32) ((float*)Cp)[(size_t)row * N + col] = acc[mi][nf][j];
        else        ((u16*)Cp)[(size_t)row * N + col]  = f2bf(acc[mi][nf][j]);
      }
    }
}

// ---------------- flash attention v11: counted vmcnt + trailing barrier ------
// v10's race FIXED: per tile, {STAGE(t+1) -> vmcnt(4) -> barrier#1 -> compute
// -> barrier#2}. barrier#2 guarantees all waves' ds_reads of buffer cur are
// complete (reads are consumed by MFMA pre-barrier) before any wave's next
// iteration stages into it. t+1's loads stay in flight across both barriers
// (T4 preserved — no vmcnt(0) drain in the loop body).
__global__ __launch_bounds__(512, 4) void k_attn(const u16* __restrict__ QKV,
                                                 const u16* __restrict__ Kr,
                                                 const u16* __restrict__ Vt,
                                                 const float2* __restrict__ tab,
                                                 const int* __restrict__ pos,
                                                 u16* __restrict__ ctx) {
  __shared__ __align__(16) u16 Ks[2][64 * 128];
  __shared__ __align__(16) u16 Vs[2][128 * 64];
  __shared__ __align__(16) u16 Ps[8][16 * 40];   // pitch 40 (80B): <=2-way banks
  const int bid = blockIdx.x;
  const int qt = 15 - (bid >> 6);          // longest-first
  const int bh = bid & 63;
  const int b = bh >> 5, h = bh & 31;
  const int kvh = h >> 2;
  const int tid = threadIdx.x;
  const int w = tid >> 6, lane = tid & 63;
  const int lrow = lane & 15, lk = lane >> 4;
  const int q0w = qt * 128 + w * 16;       // wave's first q row

  // ---- Q frags with RoPE fused (Q read once from qkvlin) ----
  const int s = q0w + lrow;
  const int p = pos[b * S_ + s];
  const u16* q0 = QKV + ((size_t)(b * S_ + s)) * NQKV_ + h * D_ + lk * 8;
  bf16x8 raw[4];
#pragma unroll
  for (int ks = 0; ks < 4; ++ks) raw[ks] = *(const bf16x8*)(q0 + ks * 32);
  bf16x8 qf[4];
#pragma unroll
  for (int ks = 0; ks < 2; ++ks)
#pragma unroll
    for (int e = 0; e < 8; ++e) {
      int d = ks * 32 + lk * 8 + e;
      float2 scv = tab[p * 64 + d];
      float x1 = bf2f((u16)raw[ks][e]), x2 = bf2f((u16)raw[ks + 2][e]);
      qf[ks][e]     = (short)f2bf(x1 * scv.y - x2 * scv.x);
      qf[ks + 2][e] = (short)f2bf(x2 * scv.y + x1 * scv.x);
    }

  float m[4] = {-1e30f, -1e30f, -1e30f, -1e30f};   // log2-domain running max
  float l[4] = {0.f, 0.f, 0.f, 0.f};
  f32x4 o[8] = {};

  const u16* kbase = Kr + (size_t)(b * KVH_ + kvh) * S_ * D_;
  const u16* vbase = Vt + (size_t)(b * KVH_ + kvh) * D_ * S_;
  const float cl = 0.12751743435f;  // (1/sqrt(128)) * log2(e)
  const int nt = 2 * qt + 2;

  auto STAGE = [&](int buf, int kb) {
    const int kv0 = kb << 6;
#pragma unroll
    for (int c = 0; c < 2; ++c) {          // K: 8 rows/wave, 4 rows/call
      int r = w * 8 + (lane >> 4) + c * 4;
      gload_lds16(kbase + (size_t)(kv0 + r) * D_ + (((lane & 15) ^ (r & 7)) << 3),
                  &Ks[buf][(w * 8 + c * 4) * 128]);
    }
#pragma unroll
    for (int c = 0; c < 2; ++c) {          // V^T: 16 rows/wave, 8 rows/call
      int r = w * 16 + (lane >> 3) + c * 8;
      gload_lds16(vbase + (size_t)r * S_ + kv0 + (((lane & 7) ^ (r & 7)) << 3),
                  &Vs[buf][(w * 16 + c * 8) * 64]);
    }
  };

  STAGE(0, 0);
  int cur = 0;
  for (int kb = 0; kb < nt; ++kb) {
    // T4: issue next stage, counted wait (tile kb's 4 oldest loads), barrier.
    if (kb + 1 < nt) {
      STAGE(cur ^ 1, kb + 1);
      asm volatile("s_waitcnt vmcnt(4)" ::: "memory");
    } else {
      asm volatile("s_waitcnt vmcnt(0)" ::: "memory");
    }
    BARRIER();                             // barrier#1: tile kb visible
    const int kv0 = kb << 6;
    if (kv0 <= q0w + 15) {                 // wave-active tile
      const u16* Kb = &Ks[cur][0];
      const u16* Vb = &Vs[cur][0];

      // S = Q K^T (16 MFMAs)
      f32x4 sc[4] = {};
      __builtin_amdgcn_s_setprio(1);
#pragma unroll
      for (int n0 = 0; n0 < 4; ++n0) {
#pragma unroll
        for (int ks = 0; ks < 4; ++ks) {
          int krow = (n0 << 4) + lrow;
          bf16x8 kf = *(const bf16x8*)(Kb + krow * 128 + ((((ks << 2) + lk) ^ (krow & 7)) << 3));
          sc[n0] = __builtin_amdgcn_mfma_f32_16x16x32_bf16(qf[ks], kf, sc[n0], 0, 0, 0);
        }
      }
      __builtin_amdgcn_s_setprio(0);

      // scale (log2 domain) + causal mask (global indices) + online softmax
      const bool diag = (kv0 + 63 > q0w);
      float mnew[4] = {m[0], m[1], m[2], m[3]};
#pragma unroll
      for (int n0 = 0; n0 < 4; ++n0)
#pragma unroll
        for (int j = 0; j < 4; ++j) {
          float v = sc[n0][j] * cl;
          if (diag && (kv0 + (n0 << 4) + lrow > q0w + (lk << 2) + j)) v = -1e30f;
          sc[n0][j] = v;
          mnew[j] = fmaxf(mnew[j], v);
        }
#pragma unroll
      for (int j = 0; j < 4; ++j) {
        float v = mnew[j];
        v = fmaxf(v, __shfl_xor(v, 1));
        v = fmaxf(v, __shfl_xor(v, 2));
        v = fmaxf(v, __shfl_xor(v, 4));
        v = fmaxf(v, __shfl_xor(v, 8));
        mnew[j] = v;
      }

      // T13 defer-max: rescale only when max grew by > 11.5 (log2) anywhere
      bool need = false;
#pragma unroll
      for (int j = 0; j < 4; ++j) need |= (mnew[j] - m[j] > 11.5f);
      if (__any(need)) {
        float alpha[4];
#pragma unroll
        for (int j = 0; j < 4; ++j) {
          alpha[j] = exp2f(m[j] - mnew[j]);
          m[j] = mnew[j];
          l[j] *= alpha[j];
        }
#pragma unroll
        for (int db = 0; db < 8; ++db)
#pragma unroll
          for (int j = 0; j < 4; ++j)
            o[db][j] *= alpha[j];
      }

      float rs[4] = {0.f, 0.f, 0.f, 0.f};
#pragma unroll
      for (int n0 = 0; n0 < 4; ++n0)
#pragma unroll
        for (int j = 0; j < 4; ++j) {
          float pv = exp2f(sc[n0][j] - m[j]);
          sc[n0][j] = pv;
          rs[j] += pv;
        }
#pragma unroll
      for (int j = 0; j < 4; ++j) {
        float v = rs[j];
        v += __shfl_xor(v, 1); v += __shfl_xor(v, 2);
        v += __shfl_xor(v, 4); v += __shfl_xor(v, 8);
        l[j] += v;
      }

      // ---- O += P V in two kv-32 halves (Ps pitch 40, reused) ----
      u16* pw = &Ps[w][0];
#pragma unroll
      for (int half = 0; half < 2; ++half) {
        // WAR fence: prior pass's reads (and writes) drained before overwrite
        asm volatile("s_waitcnt lgkmcnt(0)" ::: "memory");
#pragma unroll
        for (int n0 = 0; n0 < 2; ++n0)
#pragma unroll
          for (int j = 0; j < 4; ++j)
            pw[((lk << 2) + j) * 40 + (n0 << 4) + lrow] =
                f2bf(sc[(half << 1) + n0][j]);
        bf16x8 pf = *(const bf16x8*)(pw + lrow * 40 + (lk << 3));
        __builtin_amdgcn_s_setprio(1);
#pragma unroll
        for (int db = 0; db < 8; ++db) {
          int dr = (db << 4) + lrow;
          bf16x8 vf = *(const bf16x8*)(Vb + dr * 64 + ((((half << 2) + lk) ^ (dr & 7)) << 3));
          o[db] = __builtin_amdgcn_mfma_f32_16x16x32_bf16(pf, vf, o[db], 0, 0, 0);
        }
        __builtin_amdgcn_s_setprio(0);
      }
    }
    BARRIER();                             // barrier#2: reads of buf cur done
    cur ^= 1;
  }

#pragma unroll
  for (int j = 0; j < 4; ++j) l[j] = 1.0f / l[j];
#pragma unroll
  for (int db = 0; db < 8; ++db)
#pragma unroll
    for (int j = 0; j < 4; ++j) {
      int q = q0w + (lk << 2) + j;
      ctx[((size_t)(b * S_ + q)) * HD_ + h * D_ + (db << 4) + lrow] = f2bf(o[db][j] * l[j]);
    }
}

extern "C" void kernel_launch(void* const* d_in, const int* in_sizes, int n_in,
                              void* d_out, int out_size, void* d_ws, size_t ws_size,
                              hipStream_t stream) {
  const float* hidden = (const float*)d_in[0];
  const float* Wq = (const float*)d_in[1];
  const float* Wk = (const float*)d_in[2];
  const float* Wv = (const float*)d_in[3];
  const float* Wo = (const float*)d_in[4];
  const int* pos_ids = (const int*)d_in[7];

  char* ws = (char*)d_ws;
  u16* hs      = (u16*)(ws);                    // [0,32M)   hidden bf16; later ctx
  u16* ctx     = hs;                            //           ctx [B,S,H*D]
  u16* wqkvt   = (u16*)(ws + 33554432ull);      // [32,80M)  stacked [6144][4096]; later WoT
  u16* wot     = wqkvt;
  u16* qkvlin  = (u16*)(ws + 83886080ull);      // [80,128M) qkv_lin [M][6144]
  u16* kr      = (u16*)(ws + 134217728ull);     // [128,136M) k rope'd [B,KVH,S,D]
  u16* vt      = (u16*)(ws + 142606336ull);     // [136,144M) v^T [B,KVH,D,S]
  float2* tab  = (float2*)(ws + 150994944ull);  // [144,145M) sin/cos table

  // 1. hidden -> bf16
  k_f2bf<<<dim3((M_*E_)/1024), dim3(256), 0, stream>>>(hidden, hs, M_*E_);
  // 2. stacked W^T: rows [0,4096)=Wq^T, [4096,5120)=Wk^T, [5120,6144)=Wv^T
  k_transpose_f2bf<<<dim3(HD_/64, E_/64), dim3(256), 0, stream>>>(Wq, wqkvt, E_, HD_);
  k_transpose_f2bf<<<dim3(KVD_/64, E_/64), dim3(256), 0, stream>>>(Wk, wqkvt + (size_t)HD_*E_, E_, KVD_);
  k_transpose_f2bf<<<dim3(KVD_/64, E_/64), dim3(256), 0, stream>>>(Wv, wqkvt + (size_t)(HD_+KVD_)*E_, E_, KVD_);
  // 3. fused QKV projection: [M][6144], 256^2 8-phase
  k_gemm8<false><<<dim3((M_/256)*(NQKV_/256)), dim3(512), 0, stream>>>(hs, wqkvt, (void*)qkvlin, M_, NQKV_, E_);
  // 4. Wo^T (reuses wqkvt region; QKV GEMM done)
  k_transpose_f2bf<<<dim3(E_/64, HD_/64), dim3(256), 0, stream>>>(Wo, wot, HD_, E_);
  // 5. sin/cos table
  k_table<<<dim3((S_*64)/256), dim3(256), 0, stream>>>(tab);
  // 6. RoPE K -> kr [B,KVH,S,D] (Q rope is fused into k_attn)
  k_rope<<<dim3((B_*KVH_*S_*64)/256), dim3(256), 0, stream>>>(qkvlin + HD_, kr, tab, pos_ids, KVH_, NQKV_, B_*KVH_*S_*64);
  // 7. V transpose -> [B,KVH,D,S]
  k_transpose_v<<<dim3(S_/64, D_/64, B_*KVH_), dim3(256), 0, stream>>>(qkvlin + HD_ + KVD_, vt, NQKV_);
  // 8. flash attention v11 -> ctx (hs region; hidden no longer needed)
  k_attn<<<dim3(B_*H_*(S_/128)), dim3(512), 0, stream>>>(qkvlin, kr, vt, tab, pos_ids, ctx);
  // 9. out = ctx @ Wo (fp32 epilogue), 256^2 8-phase
  k_gemm8<true><<<dim3((M_/256)*(E_/256)), dim3(512), 0, stream>>>(ctx, wot, d_out, M_, E_, HD_);
}

// Round 15
// 576.758 us; speedup vs baseline: 1.3033x; 1.0180x over previous
//
#include <hip/hip_runtime.h>
#include <hip/hip_bf16.h>
#include <cstdint>
#include <cstddef>

#define B_ 2
#define S_ 2048
#define E_ 4096
#define H_ 32
#define KVH_ 8
#define D_ 128
#define M_ (B_*S_)      // 4096 rows (B*S)
#define HD_ (H_*D_)     // 4096
#define KVD_ (KVH_*D_)  // 1024
#define NQKV_ 6144      // HD_ + 2*KVD_

typedef unsigned short u16;
typedef __attribute__((ext_vector_type(8))) short bf16x8;
typedef __attribute__((ext_vector_type(4))) float f32x4;

__device__ __forceinline__ float bf2f(u16 u) {
  union { float f; uint32_t i; } v; v.i = ((uint32_t)u) << 16; return v.f;
}
__device__ __forceinline__ u16 f2bf(float f) {
  union { float f; uint32_t i; } v; v.f = f;
  uint32_t r = v.i + 0x7FFF + ((v.i >> 16) & 1);   // RNE
  return (u16)(r >> 16);
}

// async global->LDS, 16B per lane; LDS dest = wave-uniform base + lane*16
__device__ __forceinline__ void gload_lds16(const void* g, void* l) {
  __builtin_amdgcn_global_load_lds(
      (const __attribute__((address_space(1))) void*)g,
      (__attribute__((address_space(3))) void*)l, 16, 0, 0);
}

#define FENCE() asm volatile("" ::: "memory")
#define BARRIER() do { FENCE(); __builtin_amdgcn_s_barrier(); FENCE(); } while (0)
#define VMCNT6() asm volatile("s_waitcnt vmcnt(6)" ::: "memory")

// ---------------- elementwise f32 -> bf16 ----------------
__global__ __launch_bounds__(256) void k_f2bf(const float* __restrict__ in,
                                              u16* __restrict__ out, int n) {
  int i = (blockIdx.x * 256 + threadIdx.x) * 4;
  if (i + 3 < n) {
    float4 v = *(const float4*)(in + i);
    *(ushort4*)(out + i) = make_ushort4(f2bf(v.x), f2bf(v.y), f2bf(v.z), f2bf(v.w));
  }
}

// ------- transpose-convert f32 [R][C] -> bf16 [C][R], 64x64, ushort2 stores ----
__global__ __launch_bounds__(256) void k_transpose_f2bf(const float* __restrict__ in,
                                                        u16* __restrict__ out, int R, int C) {
  __shared__ float tile[64][65];
  const int c0 = blockIdx.x * 64, r0 = blockIdx.y * 64;
  const int tid = threadIdx.x;
  const int lx = tid & 63, ty = tid >> 6;        // loads: 64-lane rows
#pragma unroll
  for (int i = 0; i < 16; ++i)
    tile[ty + 4 * i][lx] = in[(size_t)(r0 + ty + 4 * i) * C + c0 + lx];
  __syncthreads();
  const int oy = tid & 31, xb = tid >> 5;        // stores: 32 lanes x ushort2 = 128B
#pragma unroll
  for (int i = 0; i < 8; ++i) {
    int X = xb + 8 * i;
    *(ushort2*)(out + (size_t)(c0 + X) * R + r0 + 2 * oy) =
        make_ushort2(f2bf(tile[2 * oy][X]), f2bf(tile[2 * oy + 1][X]));
  }
}

// -- transpose v cols of qkvlin -> vt [B][KVH][D][S] (bf16), 64x64 vectorized --
__global__ __launch_bounds__(256) void k_transpose_v(const u16* __restrict__ vlin,
                                                     u16* __restrict__ vt, int stride) {
  __shared__ u16 tile[64][65];
  const int bk = blockIdx.z;             // b*KVH + kvh
  const int b = bk >> 3, kvh = bk & 7;
  const int s0 = blockIdx.x * 64, d0 = blockIdx.y * 64;
  const int tid = threadIdx.x;
  const int lx = tid & 63, ty = tid >> 6;
#pragma unroll
  for (int i = 0; i < 16; ++i)
    tile[ty + 4 * i][lx] =
        vlin[(size_t)(b * S_ + s0 + ty + 4 * i) * stride + kvh * D_ + d0 + lx];
  __syncthreads();
  const int oy = tid & 31, xb = tid >> 5;
#pragma unroll
  for (int i = 0; i < 8; ++i) {
    int X = xb + 8 * i;
    *(ushort2*)(vt + ((size_t)bk * D_ + d0 + X) * S_ + s0 + 2 * oy) =
        make_ushort2(tile[2 * oy][X], tile[2 * oy + 1][X]);
  }
}

// ---------------- RoPE sin/cos table [S][64] ----------------
__global__ __launch_bounds__(256) void k_table(float2* __restrict__ tab) {
  int i = blockIdx.x * 256 + threadIdx.x;
  if (i < S_ * 64) {
    int s = i >> 6, d = i & 63;
    float inv = powf(10000.0f, -(float)d / 64.0f);
    float f = (float)s * inv;
    tab[i] = make_float2(sinf(f), cosf(f));
  }
}

// -------- RoPE + head reorder: strided cols of [B,S,*] -> [B,heads,S,D] --------
__global__ __launch_bounds__(256) void k_rope(const u16* __restrict__ in, u16* __restrict__ out,
                                              const float2* __restrict__ tab,
                                              const int* __restrict__ pos,
                                              int heads, int in_stride, int total) {
  int i = blockIdx.x * 256 + threadIdx.x;
  if (i >= total) return;
  int d = i & 63;
  int s = (i >> 6) & (S_ - 1);
  int bh = i >> 17;                 // 64*S_ = 2^17
  int h = bh % heads, b = bh / heads;
  size_t ibase = ((size_t)(b * S_ + s)) * in_stride + h * D_;
  float2 scv = tab[pos[b * S_ + s] * 64 + d];
  float x1 = bf2f(in[ibase + d]), x2 = bf2f(in[ibase + d + 64]);
  size_t obase = ((size_t)bh * S_ + s) * D_;
  out[obase + d]      = f2bf(x1 * scv.y - x2 * scv.x);
  out[obase + d + 64] = f2bf(x2 * scv.y + x1 * scv.x);
}

// ---------------- bf16 GEMM v5: 8-phase 256x256, counted vmcnt(6) ----------------
// (unchanged from round 12 — verified, 952 TF, 0 bank conflicts)
template<bool OUTF32>
__global__ __launch_bounds__(512, 2) void k_gemm8(const u16* __restrict__ A,
                                                  const u16* __restrict__ BT,
                                                  void* __restrict__ Cp,
                                                  int M, int N, int K) {
  __shared__ __align__(16) u16 L[8 * 8192];  // [buf][mat][half][128*64]
  const int tid = threadIdx.x;
  const int w = tid >> 6, lane = tid & 63;
  const int lrow = lane & 15, lk = lane >> 4;
  const int nbn = N >> 8;
  const int tm = blockIdx.x / nbn, tn = blockIdx.x % nbn;
  const int m0 = tm << 8, n0 = tn << 8;
  const int wm = w >> 2, wn = w & 3;

  f32x4 acc[8][4] = {};
  bf16x8 bres[4][2];
  const int nt = K >> 6;

  const u16* RA[2] = { &L[(0 + wm) * 8192],       &L[(4 + wm) * 8192] };
  const u16* RB[2] = { &L[(2 + (wn >> 1)) * 8192], &L[(6 + (wn >> 1)) * 8192] };

  auto STAGE = [&](int buf, int mat, int half, int t) {
    const u16* src = mat ? BT : A;
    const int base0 = mat ? n0 : m0;
    u16* reg = &L[(buf * 4 + mat * 2 + half) * 8192];
#pragma unroll
    for (int c = 0; c < 2; ++c) {
      int rl = (c << 6) + (w << 3) + (lane >> 3);
      int gb = (lane & 7) ^ (rl & 7);
      gload_lds16(src + (size_t)(base0 + (half << 7) + rl) * K + (t << 6) + (gb << 3),
                  reg + ((c << 6) + (w << 3)) * 64);
    }
  };
  auto LDB = [&](int buf) {
#pragma unroll
    for (int nf = 0; nf < 4; ++nf)
#pragma unroll
      for (int ks = 0; ks < 2; ++ks) {
        int br = ((wn & 1) << 6) + (nf << 4) + lrow;
        int cb = (ks << 2) + lk;
        bres[nf][ks] = *(const bf16x8*)(RB[buf] + br * 64 + ((cb ^ (br & 7)) << 3));
      }
  };
  auto LDA2 = [&](int buf, int mp, bf16x8 (&af)[2][2]) {
#pragma unroll
    for (int d = 0; d < 2; ++d)
#pragma unroll
      for (int ks = 0; ks < 2; ++ks) {
        int ar = (((mp << 1) + d) << 4) + lrow;
        int cb = (ks << 2) + lk;
        af[d][ks] = *(const bf16x8*)(RA[buf] + ar * 64 + ((cb ^ (ar & 7)) << 3));
      }
  };
  auto MM2 = [&](int mp, bf16x8 (&af)[2][2]) {
    __builtin_amdgcn_s_setprio(1);
#pragma unroll
    for (int ks = 0; ks < 2; ++ks)
#pragma unroll
      for (int d = 0; d < 2; ++d)
#pragma unroll
        for (int nf = 0; nf < 4; ++nf)
          acc[(mp << 1) + d][nf] = __builtin_amdgcn_mfma_f32_16x16x32_bf16(
              af[d][ks], bres[nf][ks], acc[(mp << 1) + d][nf], 0, 0, 0);
    __builtin_amdgcn_s_setprio(0);
  };

  // prologue: X.B0,X.B1,X.A0,X.A1 (tile 0), Y.B0,Y.B1 (tile 1) — 12 loads
  STAGE(0, 1, 0, 0); STAGE(0, 1, 1, 0);
  STAGE(0, 0, 0, 0); STAGE(0, 0, 1, 0);
  STAGE(1, 1, 0, 1); STAGE(1, 1, 1, 1);

  const int niter = nt >> 1;
  for (int i = 0; i < niter; ++i) {
    const int t1 = 2 * i + 1;
    const int t2 = (2 * i + 2 < nt) ? 2 * i + 2 : nt - 1;
    const int t3 = (2 * i + 3 < nt) ? 2 * i + 3 : nt - 1;
    bf16x8 afA[2][2], afB[2][2];

    // ---- K-tile 2i from buf0 ----
    STAGE(1, 0, 0, t1);                 // p0: Y.A0
    VMCNT6();                           // X.{A,B}(2i) landed
    BARRIER();
    LDB(0); LDA2(0, 0, afA);
    MM2(0, afA);
    LDA2(0, 1, afB);
    BARRIER();
    STAGE(1, 0, 1, t1);                 // p1: Y.A1
    MM2(1, afB);
    LDA2(0, 2, afA);
    BARRIER();
    STAGE(0, 1, 0, t2);                 // p2: X.B0
    MM2(2, afA);
    LDA2(0, 3, afB);
    BARRIER();
    STAGE(0, 1, 1, t2);                 // p3: X.B1
    MM2(3, afB);
    BARRIER();

    // ---- K-tile 2i+1 from buf1 ----
    STAGE(0, 0, 0, t2);                 // p4: X.A0
    VMCNT6();                           // Y.{A,B}(2i+1) landed
    BARRIER();
    LDB(1); LDA2(1, 0, afA);
    MM2(0, afA);
    LDA2(1, 1, afB);
    BARRIER();
    STAGE(0, 0, 1, t2);                 // p5: X.A1
    MM2(1, afB);
    LDA2(1, 2, afA);
    BARRIER();
    STAGE(1, 1, 0, t3);                 // p6: Y.B0
    MM2(2, afA);
    LDA2(1, 3, afB);
    BARRIER();
    STAGE(1, 1, 1, t3);                 // p7: Y.B1
    MM2(3, afB);
    BARRIER();
  }

  // epilogue: r1-verified 16x16 C/D mapping
#pragma unroll
  for (int mi = 0; mi < 8; ++mi)
#pragma unroll
    for (int nf = 0; nf < 4; ++nf) {
      int col = n0 + (wn << 6) + (nf << 4) + lrow;
#pragma unroll
      for (int j = 0; j < 4; ++j) {
        int row = m0 + (wm << 7) + (mi << 4) + (lk << 2) + j;
        if (OUTF32) ((float*)Cp)[(size_t)row * N + col] = acc[mi][nf][j];
        else        ((u16*)Cp)[(size_t)row * N + col]  = f2bf(acc[mi][nf][j]);
      }
    }
}

// ---------------- flash attention v12: MFMA row-sums + cl folded into Q -------
// v11 sync structure (verified). Softmax cost cuts:
// (1) V^T gets 16 extra rows: row 128 = 1.0 bf16, rows 129-143 = 0 (init once;
//     STAGE only writes rows <128; constant rows are swizzle-invariant).
//     PV db=8 then accumulates o[8][j] = sum_kv P[q][kv] — the row-sum l rides
//     the MFMA and is rescaled by defer-max alpha exactly like O. Removes the
//     16-shfl + 16-add sum reduction per tile.
// (2) cl = log2(e)/sqrt(D) folded into Q at RoPE time — removes 16 muls/tile.
__global__ __launch_bounds__(512, 4) void k_attn(const u16* __restrict__ QKV,
                                                 const u16* __restrict__ Kr,
                                                 const u16* __restrict__ Vt,
                                                 const float2* __restrict__ tab,
                                                 const int* __restrict__ pos,
                                                 u16* __restrict__ ctx) {
  __shared__ __align__(16) u16 Ks[2][64 * 128];
  __shared__ __align__(16) u16 Vs[2][144 * 64];  // rows 128..143 = sum rows
  __shared__ __align__(16) u16 Ps[8][16 * 40];   // pitch 40 (80B): <=2-way banks
  const int bid = blockIdx.x;
  const int qt = 15 - (bid >> 6);          // longest-first
  const int bh = bid & 63;
  const int b = bh >> 5, h = bh & 31;
  const int kvh = h >> 2;
  const int tid = threadIdx.x;
  const int w = tid >> 6, lane = tid & 63;
  const int lrow = lane & 15, lk = lane >> 4;
  const int q0w = qt * 128 + w * 16;       // wave's first q row

  // ---- Q frags with RoPE fused + cl pre-scale ----
  const float cl = 0.12751743435f;  // (1/sqrt(128)) * log2(e)
  const int s = q0w + lrow;
  const int p = pos[b * S_ + s];
  const u16* q0 = QKV + ((size_t)(b * S_ + s)) * NQKV_ + h * D_ + lk * 8;
  bf16x8 raw[4];
#pragma unroll
  for (int ks = 0; ks < 4; ++ks) raw[ks] = *(const bf16x8*)(q0 + ks * 32);
  bf16x8 qf[4];
#pragma unroll
  for (int ks = 0; ks < 2; ++ks)
#pragma unroll
    for (int e = 0; e < 8; ++e) {
      int d = ks * 32 + lk * 8 + e;
      float2 scv = tab[p * 64 + d];
      float x1 = bf2f((u16)raw[ks][e]), x2 = bf2f((u16)raw[ks + 2][e]);
      qf[ks][e]     = (short)f2bf(cl * (x1 * scv.y - x2 * scv.x));
      qf[ks + 2][e] = (short)f2bf(cl * (x2 * scv.y + x1 * scv.x));
    }

  float m[4] = {-1e30f, -1e30f, -1e30f, -1e30f};   // log2-domain running max
  f32x4 o[9] = {};                                 // o[8] = row-sum accumulator

  const u16* kbase = Kr + (size_t)(b * KVH_ + kvh) * S_ * D_;
  const u16* vbase = Vt + (size_t)(b * KVH_ + kvh) * D_ * S_;
  const int nt = 2 * qt + 2;

  auto STAGE = [&](int buf, int kb) {
    const int kv0 = kb << 6;
#pragma unroll
    for (int c = 0; c < 2; ++c) {          // K: 8 rows/wave, 4 rows/call
      int r = w * 8 + (lane >> 4) + c * 4;
      gload_lds16(kbase + (size_t)(kv0 + r) * D_ + (((lane & 15) ^ (r & 7)) << 3),
                  &Ks[buf][(w * 8 + c * 4) * 128]);
    }
#pragma unroll
    for (int c = 0; c < 2; ++c) {          // V^T: 16 rows/wave, 8 rows/call
      int r = w * 16 + (lane >> 3) + c * 8;
      gload_lds16(vbase + (size_t)r * S_ + kv0 + (((lane & 7) ^ (r & 7)) << 3),
                  &Vs[buf][(w * 16 + c * 8) * 64]);
    }
  };

  // init sum rows once: Vs row 128 = 1.0 bf16, rows 129..143 = 0 (both bufs)
  for (int i = tid; i < 16 * 64; i += 512) {
    u16 v = (i < 64) ? (u16)0x3F80 : (u16)0;
    Vs[0][128 * 64 + i] = v;
    Vs[1][128 * 64 + i] = v;
  }
  asm volatile("s_waitcnt lgkmcnt(0)" ::: "memory");  // own writes done pre-barrier

  STAGE(0, 0);
  int cur = 0;
  for (int kb = 0; kb < nt; ++kb) {
    // T4: issue next stage, counted wait (tile kb's 4 oldest loads), barrier.
    if (kb + 1 < nt) {
      STAGE(cur ^ 1, kb + 1);
      asm volatile("s_waitcnt vmcnt(4)" ::: "memory");
    } else {
      asm volatile("s_waitcnt vmcnt(0)" ::: "memory");
    }
    BARRIER();                             // barrier#1: tile kb visible
    const int kv0 = kb << 6;
    if (kv0 <= q0w + 15) {                 // wave-active tile
      const u16* Kb = &Ks[cur][0];
      const u16* Vb = &Vs[cur][0];

      // S = Q K^T (16 MFMAs) — already in log2-scaled domain (cl in Q)
      f32x4 sc[4] = {};
      __builtin_amdgcn_s_setprio(1);
#pragma unroll
      for (int n0 = 0; n0 < 4; ++n0) {
#pragma unroll
        for (int ks = 0; ks < 4; ++ks) {
          int krow = (n0 << 4) + lrow;
          bf16x8 kf = *(const bf16x8*)(Kb + krow * 128 + ((((ks << 2) + lk) ^ (krow & 7)) << 3));
          sc[n0] = __builtin_amdgcn_mfma_f32_16x16x32_bf16(qf[ks], kf, sc[n0], 0, 0, 0);
        }
      }
      __builtin_amdgcn_s_setprio(0);

      // causal mask (global indices) + row max
      const bool diag = (kv0 + 63 > q0w);
      float mnew[4] = {m[0], m[1], m[2], m[3]};
#pragma unroll
      for (int n0 = 0; n0 < 4; ++n0)
#pragma unroll
        for (int j = 0; j < 4; ++j) {
          float v = sc[n0][j];
          if (diag && (kv0 + (n0 << 4) + lrow > q0w + (lk << 2) + j)) v = -1e30f;
          sc[n0][j] = v;
          mnew[j] = fmaxf(mnew[j], v);
        }
#pragma unroll
      for (int j = 0; j < 4; ++j) {
        float v = mnew[j];
        v = fmaxf(v, __shfl_xor(v, 1));
        v = fmaxf(v, __shfl_xor(v, 2));
        v = fmaxf(v, __shfl_xor(v, 4));
        v = fmaxf(v, __shfl_xor(v, 8));
        mnew[j] = v;
      }

      // T13 defer-max: rescale only when max grew by > 11.5 (log2) anywhere
      bool need = false;
#pragma unroll
      for (int j = 0; j < 4; ++j) need |= (mnew[j] - m[j] > 11.5f);
      if (__any(need)) {
        float alpha[4];
#pragma unroll
        for (int j = 0; j < 4; ++j) {
          alpha[j] = exp2f(m[j] - mnew[j]);
          m[j] = mnew[j];
        }
#pragma unroll
        for (int db = 0; db < 9; ++db)      // includes o[8] = row-sum
#pragma unroll
          for (int j = 0; j < 4; ++j)
            o[db][j] *= alpha[j];
      }

      // P = exp2(S - m)  (row-sum now rides the PV MFMA via ones-row)
#pragma unroll
      for (int n0 = 0; n0 < 4; ++n0)
#pragma unroll
        for (int j = 0; j < 4; ++j)
          sc[n0][j] = exp2f(sc[n0][j] - m[j]);

      // ---- O += P V in two kv-32 halves (Ps pitch 40, reused) ----
      u16* pw = &Ps[w][0];
#pragma unroll
      for (int half = 0; half < 2; ++half) {
        // WAR fence: prior pass's reads (and writes) drained before overwrite
        asm volatile("s_waitcnt lgkmcnt(0)" ::: "memory");
#pragma unroll
        for (int n0 = 0; n0 < 2; ++n0)
#pragma unroll
          for (int j = 0; j < 4; ++j)
            pw[((lk << 2) + j) * 40 + (n0 << 4) + lrow] =
                f2bf(sc[(half << 1) + n0][j]);
        bf16x8 pf = *(const bf16x8*)(pw + lrow * 40 + (lk << 3));
        __builtin_amdgcn_s_setprio(1);
#pragma unroll
        for (int db = 0; db < 9; ++db) {    // db=8: ones-row -> row-sum in o[8]
          int dr = (db << 4) + lrow;
          bf16x8 vf = *(const bf16x8*)(Vb + dr * 64 + ((((half << 2) + lk) ^ (dr & 7)) << 3));
          o[db] = __builtin_amdgcn_mfma_f32_16x16x32_bf16(pf, vf, o[db], 0, 0, 0);
        }
        __builtin_amdgcn_s_setprio(0);
      }
    }
    BARRIER();                             // barrier#2: reads of buf cur done
    cur ^= 1;
  }

  // l[j] lives in o[8][j] of the lrow==0 lane of each 16-lane group
  float linv[4];
#pragma unroll
  for (int j = 0; j < 4; ++j) linv[j] = 1.0f / __shfl(o[8][j], lane & 48);
#pragma unroll
  for (int db = 0; db < 8; ++db)
#pragma unroll
    for (int j = 0; j < 4; ++j) {
      int q = q0w + (lk << 2) + j;
      ctx[((size_t)(b * S_ + q)) * HD_ + h * D_ + (db << 4) + lrow] = f2bf(o[db][j] * linv[j]);
    }
}

extern "C" void kernel_launch(void* const* d_in, const int* in_sizes, int n_in,
                              void* d_out, int out_size, void* d_ws, size_t ws_size,
                              hipStream_t stream) {
  const float* hidden = (const float*)d_in[0];
  const float* Wq = (const float*)d_in[1];
  const float* Wk = (const float*)d_in[2];
  const float* Wv = (const float*)d_in[3];
  const float* Wo = (const float*)d_in[4];
  const int* pos_ids = (const int*)d_in[7];

  char* ws = (char*)d_ws;
  u16* hs      = (u16*)(ws);                    // [0,32M)   hidden bf16; later ctx
  u16* ctx     = hs;                            //           ctx [B,S,H*D]
  u16* wqkvt   = (u16*)(ws + 33554432ull);      // [32,80M)  stacked [6144][4096]; later WoT
  u16* wot     = wqkvt;
  u16* qkvlin  = (u16*)(ws + 83886080ull);      // [80,128M) qkv_lin [M][6144]
  u16* kr      = (u16*)(ws + 134217728ull);     // [128,136M) k rope'd [B,KVH,S,D]
  u16* vt      = (u16*)(ws + 142606336ull);     // [136,144M) v^T [B,KVH,D,S]
  float2* tab  = (float2*)(ws + 150994944ull);  // [144,145M) sin/cos table

  // 1. hidden -> bf16
  k_f2bf<<<dim3((M_*E_)/1024), dim3(256), 0, stream>>>(hidden, hs, M_*E_);
  // 2. stacked W^T: rows [0,4096)=Wq^T, [4096,5120)=Wk^T, [5120,6144)=Wv^T
  k_transpose_f2bf<<<dim3(HD_/64, E_/64), dim3(256), 0, stream>>>(Wq, wqkvt, E_, HD_);
  k_transpose_f2bf<<<dim3(KVD_/64, E_/64), dim3(256), 0, stream>>>(Wk, wqkvt + (size_t)HD_*E_, E_, KVD_);
  k_transpose_f2bf<<<dim3(KVD_/64, E_/64), dim3(256), 0, stream>>>(Wv, wqkvt + (size_t)(HD_+KVD_)*E_, E_, KVD_);
  // 3. fused QKV projection: [M][6144], 256^2 8-phase
  k_gemm8<false><<<dim3((M_/256)*(NQKV_/256)), dim3(512), 0, stream>>>(hs, wqkvt, (void*)qkvlin, M_, NQKV_, E_);
  // 4. Wo^T (reuses wqkvt region; QKV GEMM done)
  k_transpose_f2bf<<<dim3(E_/64, HD_/64), dim3(256), 0, stream>>>(Wo, wot, HD_, E_);
  // 5. sin/cos table
  k_table<<<dim3((S_*64)/256), dim3(256), 0, stream>>>(tab);
  // 6. RoPE K -> kr [B,KVH,S,D] (Q rope is fused into k_attn)
  k_rope<<<dim3((B_*KVH_*S_*64)/256), dim3(256), 0, stream>>>(qkvlin + HD_, kr, tab, pos_ids, KVH_, NQKV_, B_*KVH_*S_*64);
  // 7. V transpose -> [B,KVH,D,S]
  k_transpose_v<<<dim3(S_/64, D_/64, B_*KVH_), dim3(256), 0, stream>>>(qkvlin + HD_ + KVD_, vt, NQKV_);
  // 8. flash attention v12 -> ctx (hs region; hidden no longer needed)
  k_attn<<<dim3(B_*H_*(S_/128)), dim3(512), 0, stream>>>(qkvlin, kr, vt, tab, pos_ids, ctx);
  // 9. out = ctx @ Wo (fp32 epilogue), 256^2 8-phase
  k_gemm8<true><<<dim3((M_/256)*(E_/256)), dim3(512), 0, stream>>>(ctx, wot, d_out, M_, E_, HD_);
}